// Round 6
// baseline (500.698 us; speedup 1.0000x reference)
//
#include <hip/hip_runtime.h>
#include <hip/hip_bf16.h>
#include <math.h>

#define A_TOK 4096
#define DDIM  1024
#define NEXP  8
#define FDIM  2816

typedef __bf16 bf16_t;
typedef __bf16 bf16x8 __attribute__((ext_vector_type(8)));
typedef __bf16 bf16x4 __attribute__((ext_vector_type(4)));
typedef float  f32x4  __attribute__((ext_vector_type(4)));

// ======================= workspace layout =======================
//   [0,16384)      int   idx_a[4096]
//   [16384,32768)  float gate_a[4096]
//   [32832,32868)  int   offsets[9]
//   [33280,49664)  int   perm[4096]
static constexpr size_t OFF_XS   = 65536;
static constexpr size_t OFF_XR   = OFF_XS   + (size_t)A_TOK * DDIM * 2;
static constexpr size_t OFF_MIDS = OFF_XR   + (size_t)(A_TOK + 128) * DDIM * 2;
static constexpr size_t OFF_MIDR = OFF_MIDS + (size_t)A_TOK * FDIM * 2;
static constexpr size_t OFF_W1T  = OFF_MIDR + (size_t)(A_TOK + 128) * FDIM * 2;
static constexpr size_t OFF_W3T  = OFF_W1T  + (size_t)NEXP * DDIM * FDIM * 2;
static constexpr size_t OFF_W2T  = OFF_W3T  + (size_t)NEXP * DDIM * FDIM * 2;
static constexpr size_t OFF_WS1T = OFF_W2T  + (size_t)NEXP * DDIM * FDIM * 2;
static constexpr size_t OFF_WS3T = OFF_WS1T + (size_t)DDIM * FDIM * 2;
static constexpr size_t OFF_WS2T = OFF_WS3T + (size_t)DDIM * FDIM * 2;
static constexpr size_t WS_NEED  = OFF_WS2T + (size_t)DDIM * FDIM * 2;   // ~209.5 MiB

// ======================= router: scores =======================
__global__ __launch_bounds__(256)
void score_kernel(const float* __restrict__ x,
                  const float* __restrict__ router,
                  int* __restrict__ idx_a,
                  float* __restrict__ gate_a)
{
    __shared__ float rT[NEXP][DDIM];
    const int tid = threadIdx.x;
    for (int i = tid; i < DDIM * NEXP; i += 256)
        rT[i & 7][i >> 3] = router[i];
    __syncthreads();

    const int wid = tid >> 6, lane = tid & 63;
    const int t = blockIdx.x * 4 + wid;
    const float* xr = x + (size_t)t * DDIM;

    double s[NEXP];
#pragma unroll
    for (int e = 0; e < NEXP; ++e) s[e] = 0.0;
#pragma unroll
    for (int i = 0; i < DDIM / 64; ++i) {
        int d = i * 64 + lane;
        float xv = xr[d];
#pragma unroll
        for (int e = 0; e < NEXP; ++e)
            s[e] += (double)xv * (double)rT[e][d];
    }
#pragma unroll
    for (int e = 0; e < NEXP; ++e) {
#pragma unroll
        for (int off = 32; off > 0; off >>= 1)
            s[e] += __shfl_xor(s[e], off);
    }
    if (lane == 0) {
        int best = 0; double bv = s[0];
#pragma unroll
        for (int e = 1; e < NEXP; ++e)
            if (s[e] > bv) { bv = s[e]; best = e; }
        idx_a[t] = best;
        gate_a[t] = 1.0f / (1.0f + expf(-(float)bv));
    }
}

// ======================= fused count + scan + scatter =======================
__global__ __launch_bounds__(1024)
void perm_kernel(const int* __restrict__ idx_a,
                 int* __restrict__ offsets,
                 int* __restrict__ perm)
{
    __shared__ int cnt[NEXP];
    __shared__ int base[NEXP];
    const int tid = threadIdx.x;
    if (tid < NEXP) cnt[tid] = 0;
    __syncthreads();

    int e[4];
#pragma unroll
    for (int j = 0; j < 4; ++j) {
        e[j] = idx_a[j * 1024 + tid];
        atomicAdd(&cnt[e[j]], 1);
    }
    __syncthreads();
    if (tid == 0) {
        int acc = 0;
#pragma unroll
        for (int k = 0; k < NEXP; ++k) {
            base[k] = acc; offsets[k] = acc; acc += cnt[k];
        }
        offsets[NEXP] = acc;
    }
    __syncthreads();
#pragma unroll
    for (int j = 0; j < 4; ++j) {
        int t = j * 1024 + tid;
        int pos = atomicAdd(&base[e[j]], 1);
        perm[pos] = t;
    }
}

// ======================= prep kernels =======================
__global__ void prep_x_kernel(const float* __restrict__ x,
                              const float* __restrict__ gate_a,
                              const int* __restrict__ perm,
                              bf16_t* __restrict__ xs,
                              bf16_t* __restrict__ xr)
{
    const int p = blockIdx.x;
    const int d = threadIdx.x * 4;
    float4 v = *(const float4*)(x + (size_t)p * DDIM + d);
    bf16x4 o;
    o[0] = (bf16_t)v.x; o[1] = (bf16_t)v.y; o[2] = (bf16_t)v.z; o[3] = (bf16_t)v.w;
    *(bf16x4*)(xs + (size_t)p * DDIM + d) = o;

    const int tok = perm[p];
    const float g = gate_a[tok];
    float4 w = *(const float4*)(x + (size_t)tok * DDIM + d);
    bf16x4 o2;
    o2[0] = (bf16_t)(w.x * g); o2[1] = (bf16_t)(w.y * g);
    o2[2] = (bf16_t)(w.z * g); o2[3] = (bf16_t)(w.w * g);
    *(bf16x4*)(xr + (size_t)p * DDIM + d) = o2;
}

// transpose+convert core: src [R][C] fp32 -> dst [C][R] bf16, one 64x64 tile
__device__ __forceinline__ void tconv_tile(const float* __restrict__ src,
                                           bf16_t* __restrict__ dst,
                                           int R, int C, int r0, int c0)
{
    __shared__ __align__(16) bf16_t t[64][72];
    const int tid = threadIdx.x;
    const int rl = tid >> 4;
    const int cl = (tid & 15) * 4;
#pragma unroll
    for (int i = 0; i < 4; ++i) {
        float4 v = *(const float4*)(src + (size_t)(r0 + rl + i * 16) * C + c0 + cl);
        t[cl + 0][rl + i * 16] = (bf16_t)v.x;
        t[cl + 1][rl + i * 16] = (bf16_t)v.y;
        t[cl + 2][rl + i * 16] = (bf16_t)v.z;
        t[cl + 3][rl + i * 16] = (bf16_t)v.w;
    }
    __syncthreads();
    const int cl2 = tid >> 3;
    const int rl2 = (tid & 7) * 8;
#pragma unroll
    for (int i = 0; i < 2; ++i) {
        int c = cl2 + i * 32;
        bf16x8 vv = *(const bf16x8*)&t[c][rl2];
        *(bf16x8*)(dst + (size_t)(c0 + c) * R + r0 + rl2) = vv;
    }
}

__global__ void tconvA_kernel(const float* __restrict__ w1, const float* __restrict__ w3,
                              const float* __restrict__ ws1, const float* __restrict__ ws3,
                              bf16_t* __restrict__ w1T, bf16_t* __restrict__ w3T,
                              bf16_t* __restrict__ ws1T, bf16_t* __restrict__ ws3T)
{
    const int z = blockIdx.z;
    const size_t ms = (size_t)DDIM * FDIM;
    const float* src; bf16_t* dst;
    if (z < 8)       { src = w1 + (size_t)z * ms;       dst = w1T + (size_t)z * ms; }
    else if (z < 16) { src = w3 + (size_t)(z - 8) * ms; dst = w3T + (size_t)(z - 8) * ms; }
    else if (z == 16){ src = ws1;                        dst = ws1T; }
    else             { src = ws3;                        dst = ws3T; }
    tconv_tile(src, dst, DDIM, FDIM, blockIdx.y * 64, blockIdx.x * 64);
}

__global__ void tconvB_kernel(const float* __restrict__ w2, const float* __restrict__ ws2,
                              bf16_t* __restrict__ w2T, bf16_t* __restrict__ ws2T)
{
    const int z = blockIdx.z;
    const size_t ms = (size_t)DDIM * FDIM;
    const float* src; bf16_t* dst;
    if (z < 8) { src = w2 + (size_t)z * ms; dst = w2T + (size_t)z * ms; }
    else       { src = ws2;                  dst = ws2T; }
    tconv_tile(src, dst, FDIM, DDIM, blockIdx.y * 64, blockIdx.x * 64);
}

// ======================= bf16 GEMM machinery =======================
__device__ __forceinline__ void glds16(const bf16_t* g, bf16_t* l)
{
    __builtin_amdgcn_global_load_lds(
        (const __attribute__((address_space(1))) void*)g,
        (__attribute__((address_space(3))) void*)l, 16, 0, 0);
}

// stage 128 rows x 64 bf16 (128B/row), XOR-swizzled on 16B slots (8 slots/row):
// LDS[row][slot] = global[row][slot ^ (row&7)]   -- measured 0 bank conflicts (R3/R5)
__device__ __forceinline__ void stage_swz(const bf16_t* __restrict__ src,
                                          size_t stride, bf16_t* lds, int tid)
{
#pragma unroll
    for (int i = 0; i < 4; ++i) {
        int o = i * 256 + tid;
        int row = o >> 3;
        int slot = o & 7;
        int srcSlot = slot ^ (row & 7);
        glds16(src + (size_t)row * stride + srcSlot * 8, lds + (size_t)o * 8);
    }
}

__device__ __forceinline__ int swz_off(int row, int g16)
{
    return row * 128 + ((g16 ^ (row & 7)) << 4);
}

// NOTE (R5 post-mortem): XCD-chunked remap halved FETCH_SIZE (292->151MB) but
// SLOWED gemm1 (120.7 -> 129.3 us; MfmaUtil 34.6 -> 31.2). Kernel is
// latency-bound, not HBM-bound -> remap reverted. Occupancy is the lever:
// 48KB LDS x 3 = 144KB <= 160KB, VGPR 108 <= 170 -> 3 blocks/CU.

// GEMM1: mid = silu(A@W1T^T) * (A@W3T^T); 128x128 tile, BK=64, single buffer
__global__ __launch_bounds__(256, 3)
void gemm1_bf16(const bf16_t* __restrict__ xr, const bf16_t* __restrict__ xs,
                const bf16_t* __restrict__ w1T, const bf16_t* __restrict__ w3T,
                const bf16_t* __restrict__ ws1T, const bf16_t* __restrict__ ws3T,
                const int* __restrict__ offsets,
                bf16_t* __restrict__ mid_r, bf16_t* __restrict__ mid_s)
{
    const int g  = blockIdx.z;
    const int n0 = blockIdx.x * 128;
    int m0, mEnd;
    const bf16_t *pa, *pw1, *pw3;
    bf16_t* pout;
    if (g < NEXP) {
        int s = offsets[g], e = offsets[g + 1];
        m0 = s + blockIdx.y * 128;
        if (m0 >= e) return;
        mEnd = e;
        pa = xr;
        pw1 = w1T + (size_t)g * DDIM * FDIM;
        pw3 = w3T + (size_t)g * DDIM * FDIM;
        pout = mid_r;
    } else {
        m0 = blockIdx.y * 128;
        mEnd = A_TOK;
        pa = xs; pw1 = ws1T; pw3 = ws3T; pout = mid_s;
    }

    __shared__ __align__(16) bf16_t sA[128 * 64];
    __shared__ __align__(16) bf16_t sB1[128 * 64];
    __shared__ __align__(16) bf16_t sB3[128 * 64];

    const int tid  = threadIdx.x;
    const int lane = tid & 63;
    const int wid  = tid >> 6;
    const int wm   = wid >> 1, wn = wid & 1;
    const int fr   = lane & 15;
    const int fq   = lane >> 4;

    f32x4 acc1[4][4], acc3[4][4];
#pragma unroll
    for (int i = 0; i < 4; ++i)
#pragma unroll
        for (int j = 0; j < 4; ++j) {
            acc1[i][j] = (f32x4){0.f, 0.f, 0.f, 0.f};
            acc3[i][j] = (f32x4){0.f, 0.f, 0.f, 0.f};
        }

    const bf16_t* srcA  = pa  + (size_t)m0 * DDIM;
    const bf16_t* srcB1 = pw1 + (size_t)n0 * DDIM;
    const bf16_t* srcB3 = pw3 + (size_t)n0 * DDIM;

    for (int k0 = 0; k0 < DDIM; k0 += 64) {
        stage_swz(srcA  + k0, DDIM, sA,  tid);
        stage_swz(srcB1 + k0, DDIM, sB1, tid);
        stage_swz(srcB3 + k0, DDIM, sB3, tid);
        __syncthreads();

#pragma unroll
        for (int s = 0; s < 2; ++s) {
            const int kg = s * 4 + fq;
            bf16x8 af[4], b1f[4], b3f[4];
#pragma unroll
            for (int mi = 0; mi < 4; ++mi) {
                int r = wm * 64 + mi * 16 + fr;
                af[mi] = *(const bf16x8*)((const char*)sA + swz_off(r, kg));
            }
#pragma unroll
            for (int ni = 0; ni < 4; ++ni) {
                int r = wn * 64 + ni * 16 + fr;
                b1f[ni] = *(const bf16x8*)((const char*)sB1 + swz_off(r, kg));
                b3f[ni] = *(const bf16x8*)((const char*)sB3 + swz_off(r, kg));
            }
#pragma unroll
            for (int mi = 0; mi < 4; ++mi)
#pragma unroll
                for (int ni = 0; ni < 4; ++ni) {
                    acc1[mi][ni] = __builtin_amdgcn_mfma_f32_16x16x32_bf16(af[mi], b1f[ni], acc1[mi][ni], 0, 0, 0);
                    acc3[mi][ni] = __builtin_amdgcn_mfma_f32_16x16x32_bf16(af[mi], b3f[ni], acc3[mi][ni], 0, 0, 0);
                }
        }
        __syncthreads();
    }

#pragma unroll
    for (int mi = 0; mi < 4; ++mi) {
        int prow_b = m0 + wm * 64 + mi * 16 + fq * 4;
#pragma unroll
        for (int r = 0; r < 4; ++r) {
            int prow = prow_b + r;
            if (prow < mEnd) {
#pragma unroll
                for (int ni = 0; ni < 4; ++ni) {
                    float h1 = acc1[mi][ni][r];
                    float h3 = acc3[mi][ni][r];
                    float vv = h1 / (1.0f + __expf(-h1)) * h3;
                    int col = n0 + wn * 64 + ni * 16 + fr;
                    pout[(size_t)prow * FDIM + col] = (bf16_t)vv;
                }
            }
        }
    }
}

// GEMM2: out = mid @ W2; 128x128 tile, BK=64, single buffer.
// 32KB LDS x 4 = 128KB <= 160KB, VGPR 108 <= 128 -> 4 blocks/CU.
template <bool ROUTED>
__global__ __launch_bounds__(256, 4)
void gemm2_bf16(const bf16_t* __restrict__ mid, const bf16_t* __restrict__ w2T,
                const int* __restrict__ perm, const int* __restrict__ offsets,
                float* __restrict__ out)
{
    const int n0 = blockIdx.x * 128;
    int m0, mEnd;
    const bf16_t* pb;
    if (ROUTED) {
        int g = blockIdx.z;
        int s = offsets[g], e = offsets[g + 1];
        m0 = s + blockIdx.y * 128;
        if (m0 >= e) return;
        mEnd = e;
        pb = w2T + (size_t)g * DDIM * FDIM;
    } else {
        m0 = blockIdx.y * 128;
        mEnd = A_TOK;
        pb = w2T;
    }

    __shared__ __align__(16) bf16_t sA[128 * 64];
    __shared__ __align__(16) bf16_t sB[128 * 64];

    const int tid  = threadIdx.x;
    const int lane = tid & 63;
    const int wid  = tid >> 6;
    const int wm   = wid >> 1, wn = wid & 1;
    const int fr   = lane & 15;
    const int fq   = lane >> 4;

    f32x4 acc[4][4];
#pragma unroll
    for (int i = 0; i < 4; ++i)
#pragma unroll
        for (int j = 0; j < 4; ++j)
            acc[i][j] = (f32x4){0.f, 0.f, 0.f, 0.f};

    const bf16_t* srcA = mid + (size_t)m0 * FDIM;
    const bf16_t* srcB = pb  + (size_t)n0 * FDIM;

    for (int k0 = 0; k0 < FDIM; k0 += 64) {
        stage_swz(srcA + k0, FDIM, sA, tid);
        stage_swz(srcB + k0, FDIM, sB, tid);
        __syncthreads();

#pragma unroll
        for (int s = 0; s < 2; ++s) {
            const int kg = s * 4 + fq;
            bf16x8 af[4], bf[4];
#pragma unroll
            for (int mi = 0; mi < 4; ++mi) {
                int r = wm * 64 + mi * 16 + fr;
                af[mi] = *(const bf16x8*)((const char*)sA + swz_off(r, kg));
            }
#pragma unroll
            for (int ni = 0; ni < 4; ++ni) {
                int r = wn * 64 + ni * 16 + fr;
                bf[ni] = *(const bf16x8*)((const char*)sB + swz_off(r, kg));
            }
#pragma unroll
            for (int mi = 0; mi < 4; ++mi)
#pragma unroll
                for (int ni = 0; ni < 4; ++ni)
                    acc[mi][ni] = __builtin_amdgcn_mfma_f32_16x16x32_bf16(af[mi], bf[ni], acc[mi][ni], 0, 0, 0);
        }
        __syncthreads();
    }

#pragma unroll
    for (int mi = 0; mi < 4; ++mi) {
        int prow_b = m0 + wm * 64 + mi * 16 + fq * 4;
#pragma unroll
        for (int r = 0; r < 4; ++r) {
            int prow = prow_b + r;
            if (prow < mEnd) {
                int orow = ROUTED ? perm[prow] : prow;
#pragma unroll
                for (int ni = 0; ni < 4; ++ni) {
                    int col = n0 + wn * 64 + ni * 16 + fr;
                    float vv = acc[mi][ni][r];
                    if (ROUTED)
                        out[(size_t)orow * DDIM + col] += vv;
                    else
                        out[(size_t)orow * DDIM + col] = vv;
                }
            }
        }
    }
}

// ======================= launch =======================
extern "C" void kernel_launch(void* const* d_in, const int* in_sizes, int n_in,
                              void* d_out, int out_size, void* d_ws, size_t ws_size,
                              hipStream_t stream)
{
    const float* x      = (const float*)d_in[0];
    const float* router = (const float*)d_in[1];
    const float* w1     = (const float*)d_in[2];
    const float* w3     = (const float*)d_in[3];
    const float* w2     = (const float*)d_in[4];
    const float* ws1    = (const float*)d_in[5];
    const float* ws3    = (const float*)d_in[6];
    const float* ws2    = (const float*)d_in[7];
    float* out = (float*)d_out;

    char* ws = (char*)d_ws;
    int*   idx_a   = (int*)(ws + 0);
    float* gate_a  = (float*)(ws + 16384);
    int*   offsets = (int*)(ws + 32832);
    int*   perm    = (int*)(ws + 33280);

    bf16_t* xs    = (bf16_t*)(ws + OFF_XS);
    bf16_t* xr    = (bf16_t*)(ws + OFF_XR);
    bf16_t* mid_s = (bf16_t*)(ws + OFF_MIDS);
    bf16_t* mid_r = (bf16_t*)(ws + OFF_MIDR);
    bf16_t* w1T   = (bf16_t*)(ws + OFF_W1T);
    bf16_t* w3T   = (bf16_t*)(ws + OFF_W3T);
    bf16_t* w2T   = (bf16_t*)(ws + OFF_W2T);
    bf16_t* ws1T  = (bf16_t*)(ws + OFF_WS1T);
    bf16_t* ws3T  = (bf16_t*)(ws + OFF_WS3T);
    bf16_t* ws2T  = (bf16_t*)(ws + OFF_WS2T);

    score_kernel<<<A_TOK / 4, 256, 0, stream>>>(x, router, idx_a, gate_a);
    perm_kernel<<<1, 1024, 0, stream>>>(idx_a, offsets, perm);

    prep_x_kernel<<<A_TOK, 256, 0, stream>>>(x, gate_a, perm, xs, xr);
    tconvA_kernel<<<dim3(FDIM / 64, DDIM / 64, 18), 256, 0, stream>>>(
        w1, w3, ws1, ws3, w1T, w3T, ws1T, ws3T);

    gemm1_bf16<<<dim3(FDIM / 128, 32, NEXP + 1), 256, 0, stream>>>(
        xr, xs, w1T, w3T, ws1T, ws3T, offsets, mid_r, mid_s);

    tconvB_kernel<<<dim3(DDIM / 64, FDIM / 64, 9), 256, 0, stream>>>(
        w2, ws2, w2T, ws2T);

    gemm2_bf16<false><<<dim3(DDIM / 128, 32, 1), 256, 0, stream>>>(
        mid_s, ws2T, perm, offsets, out);
    gemm2_bf16<true><<<dim3(DDIM / 128, 32, NEXP), 256, 0, stream>>>(
        mid_r, w2T, perm, offsets, out);
}

// Round 7
// 388.289 us; speedup vs baseline: 1.2895x; 1.2895x over previous
//
#include <hip/hip_runtime.h>
#include <hip/hip_bf16.h>
#include <math.h>

#define A_TOK 4096
#define DDIM  1024
#define NEXP  8
#define FDIM  2816

typedef __bf16 bf16_t;
typedef __bf16 bf16x8 __attribute__((ext_vector_type(8)));
typedef __bf16 bf16x4 __attribute__((ext_vector_type(4)));
typedef __bf16 bf16x2 __attribute__((ext_vector_type(2)));
typedef float  f32x4  __attribute__((ext_vector_type(4)));

// ======================= workspace layout =======================
//   [0,16384)      int   idx_a[4096]
//   [16384,32768)  float gate_a[4096]
//   [32832,32868)  int   offsets[9]
//   [33280,49664)  int   perm[4096]
static constexpr size_t OFF_XS   = 65536;
static constexpr size_t OFF_XR   = OFF_XS   + (size_t)A_TOK * DDIM * 2;
static constexpr size_t OFF_MIDS = OFF_XR   + (size_t)(A_TOK + 128) * DDIM * 2;
static constexpr size_t OFF_MIDR = OFF_MIDS + (size_t)A_TOK * FDIM * 2;
static constexpr size_t OFF_W1T  = OFF_MIDR + (size_t)(A_TOK + 128) * FDIM * 2;
static constexpr size_t OFF_W3T  = OFF_W1T  + (size_t)NEXP * DDIM * FDIM * 2;
static constexpr size_t OFF_W2T  = OFF_W3T  + (size_t)NEXP * DDIM * FDIM * 2;
static constexpr size_t OFF_WS1T = OFF_W2T  + (size_t)NEXP * DDIM * FDIM * 2;
static constexpr size_t OFF_WS3T = OFF_WS1T + (size_t)DDIM * FDIM * 2;
static constexpr size_t OFF_WS2T = OFF_WS3T + (size_t)DDIM * FDIM * 2;
static constexpr size_t WS_NEED  = OFF_WS2T + (size_t)DDIM * FDIM * 2;   // ~209.5 MiB

// Tuning ledger (measured):
//  R3: GEMMs (256,2), BK=64, 8-slot XOR swizzle, single buffer -> gemm1 120.7us,
//      MfmaUtil 34.6, 0 bank conflicts. BEST.
//  R4: BK=32 dbuf + __syncthreads prefetch -> conflicts 8.9e6, vmcnt(0) drain
//      at barrier kills prefetch. REVERTED.
//  R5: XCD remap -> FETCH 292->151MB but 120.7->129.3us (latency-bound, not
//      HBM-bound). REVERTED.
//  R6: launch_bounds(256,3) -> allocator targeted 84 VGPR, spilled acc to
//      scratch (WRITE 45->93MB), 232us. REVERTED. Keep (256,2).

// ======================= router: scores =======================
__global__ __launch_bounds__(256)
void score_kernel(const float* __restrict__ x,
                  const float* __restrict__ router,
                  int* __restrict__ idx_a,
                  float* __restrict__ gate_a)
{
    __shared__ float rT[NEXP][DDIM];
    const int tid = threadIdx.x;
    for (int i = tid; i < DDIM * NEXP; i += 256)
        rT[i & 7][i >> 3] = router[i];
    __syncthreads();

    const int wid = tid >> 6, lane = tid & 63;
    const int t = blockIdx.x * 4 + wid;
    const float* xr = x + (size_t)t * DDIM;

    double s[NEXP];
#pragma unroll
    for (int e = 0; e < NEXP; ++e) s[e] = 0.0;
#pragma unroll
    for (int i = 0; i < DDIM / 64; ++i) {
        int d = i * 64 + lane;
        float xv = xr[d];
#pragma unroll
        for (int e = 0; e < NEXP; ++e)
            s[e] += (double)xv * (double)rT[e][d];
    }
#pragma unroll
    for (int e = 0; e < NEXP; ++e) {
#pragma unroll
        for (int off = 32; off > 0; off >>= 1)
            s[e] += __shfl_xor(s[e], off);
    }
    if (lane == 0) {
        int best = 0; double bv = s[0];
#pragma unroll
        for (int e = 1; e < NEXP; ++e)
            if (s[e] > bv) { bv = s[e]; best = e; }
        idx_a[t] = best;
        gate_a[t] = 1.0f / (1.0f + expf(-(float)bv));
    }
}

// ======================= fused count + scan + scatter =======================
__global__ __launch_bounds__(1024)
void perm_kernel(const int* __restrict__ idx_a,
                 int* __restrict__ offsets,
                 int* __restrict__ perm)
{
    __shared__ int cnt[NEXP];
    __shared__ int base[NEXP];
    const int tid = threadIdx.x;
    if (tid < NEXP) cnt[tid] = 0;
    __syncthreads();

    int e[4];
#pragma unroll
    for (int j = 0; j < 4; ++j) {
        e[j] = idx_a[j * 1024 + tid];
        atomicAdd(&cnt[e[j]], 1);
    }
    __syncthreads();
    if (tid == 0) {
        int acc = 0;
#pragma unroll
        for (int k = 0; k < NEXP; ++k) {
            base[k] = acc; offsets[k] = acc; acc += cnt[k];
        }
        offsets[NEXP] = acc;
    }
    __syncthreads();
#pragma unroll
    for (int j = 0; j < 4; ++j) {
        int t = j * 1024 + tid;
        int pos = atomicAdd(&base[e[j]], 1);
        perm[pos] = t;
    }
}

// ======================= prep kernels =======================
__global__ void prep_x_kernel(const float* __restrict__ x,
                              const float* __restrict__ gate_a,
                              const int* __restrict__ perm,
                              bf16_t* __restrict__ xs,
                              bf16_t* __restrict__ xr)
{
    const int p = blockIdx.x;
    const int d = threadIdx.x * 4;
    float4 v = *(const float4*)(x + (size_t)p * DDIM + d);
    bf16x4 o;
    o[0] = (bf16_t)v.x; o[1] = (bf16_t)v.y; o[2] = (bf16_t)v.z; o[3] = (bf16_t)v.w;
    *(bf16x4*)(xs + (size_t)p * DDIM + d) = o;

    const int tok = perm[p];
    const float g = gate_a[tok];
    float4 w = *(const float4*)(x + (size_t)tok * DDIM + d);
    bf16x4 o2;
    o2[0] = (bf16_t)(w.x * g); o2[1] = (bf16_t)(w.y * g);
    o2[2] = (bf16_t)(w.z * g); o2[3] = (bf16_t)(w.w * g);
    *(bf16x4*)(xr + (size_t)p * DDIM + d) = o2;
}

// pack two fp32 rows' element into one u32 of 2 bf16 (low = first row)
__device__ __forceinline__ unsigned pk2(float a, float b)
{
    union { bf16x2 v; unsigned u; } x;
    x.v[0] = (bf16_t)a; x.v[1] = (bf16_t)b;
    return x.u;
}

// transpose+convert core: src [R][C] fp32 -> dst [C][R] bf16, one 64x64 tile.
// R7 rewrite: u32-packed LDS (stride 33 dwords: writes 2-way-free, reads
// spread over all 32 banks), 8 ds_write_b32 + 8 ds_read_b32 per thread
// (was 16 subword ds_write_u16).
__device__ __forceinline__ void tconv_tile(const float* __restrict__ src,
                                           bf16_t* __restrict__ dst,
                                           int R, int C, int r0, int c0)
{
    __shared__ unsigned t2[64][33];
    const int tid = threadIdx.x;
    const int cl = (tid & 15) * 4;        // cols cl..cl+3
    const int rh = tid >> 4;              // row-pair 0..15
#pragma unroll
    for (int i = 0; i < 2; ++i) {
        const int r = rh * 2 + i * 32;    // rows r, r+1
        const float* s0 = src + (size_t)(r0 + r) * C + c0 + cl;
        float4 v0 = *(const float4*)s0;
        float4 v1 = *(const float4*)(s0 + C);
        t2[cl + 0][rh + i * 16] = pk2(v0.x, v1.x);
        t2[cl + 1][rh + i * 16] = pk2(v0.y, v1.y);
        t2[cl + 2][rh + i * 16] = pk2(v0.z, v1.z);
        t2[cl + 3][rh + i * 16] = pk2(v0.w, v1.w);
    }
    __syncthreads();
    const int c2 = tid >> 3;              // 0..31
    const int rq = (tid & 7) * 4;         // row-pair base 0..28
#pragma unroll
    for (int i = 0; i < 2; ++i) {
        const int c = c2 + i * 32;
        uint4 vv;
        vv.x = t2[c][rq + 0];
        vv.y = t2[c][rq + 1];
        vv.z = t2[c][rq + 2];
        vv.w = t2[c][rq + 3];
        *(uint4*)(dst + (size_t)(c0 + c) * R + r0 + rq * 2) = vv;
    }
}

__global__ void tconvA_kernel(const float* __restrict__ w1, const float* __restrict__ w3,
                              const float* __restrict__ ws1, const float* __restrict__ ws3,
                              bf16_t* __restrict__ w1T, bf16_t* __restrict__ w3T,
                              bf16_t* __restrict__ ws1T, bf16_t* __restrict__ ws3T)
{
    const int z = blockIdx.z;
    const size_t ms = (size_t)DDIM * FDIM;
    const float* src; bf16_t* dst;
    if (z < 8)       { src = w1 + (size_t)z * ms;       dst = w1T + (size_t)z * ms; }
    else if (z < 16) { src = w3 + (size_t)(z - 8) * ms; dst = w3T + (size_t)(z - 8) * ms; }
    else if (z == 16){ src = ws1;                        dst = ws1T; }
    else             { src = ws3;                        dst = ws3T; }
    tconv_tile(src, dst, DDIM, FDIM, blockIdx.y * 64, blockIdx.x * 64);
}

__global__ void tconvB_kernel(const float* __restrict__ w2, const float* __restrict__ ws2,
                              bf16_t* __restrict__ w2T, bf16_t* __restrict__ ws2T)
{
    const int z = blockIdx.z;
    const size_t ms = (size_t)DDIM * FDIM;
    const float* src; bf16_t* dst;
    if (z < 8) { src = w2 + (size_t)z * ms; dst = w2T + (size_t)z * ms; }
    else       { src = ws2;                  dst = ws2T; }
    tconv_tile(src, dst, FDIM, DDIM, blockIdx.y * 64, blockIdx.x * 64);
}

// ======================= bf16 GEMM machinery =======================
__device__ __forceinline__ void glds16(const bf16_t* g, bf16_t* l)
{
    __builtin_amdgcn_global_load_lds(
        (const __attribute__((address_space(1))) void*)g,
        (__attribute__((address_space(3))) void*)l, 16, 0, 0);
}

// stage 128 rows x 64 bf16 (128B/row), XOR-swizzled on 16B slots (8 slots/row):
// LDS[row][slot] = global[row][slot ^ (row&7)]   -- measured 0 bank conflicts (R3/R5)
__device__ __forceinline__ void stage_swz(const bf16_t* __restrict__ src,
                                          size_t stride, bf16_t* lds, int tid)
{
#pragma unroll
    for (int i = 0; i < 4; ++i) {
        int o = i * 256 + tid;
        int row = o >> 3;
        int slot = o & 7;
        int srcSlot = slot ^ (row & 7);
        glds16(src + (size_t)row * stride + srcSlot * 8, lds + (size_t)o * 8);
    }
}

__device__ __forceinline__ int swz_off(int row, int g16)
{
    return row * 128 + ((g16 ^ (row & 7)) << 4);
}

// GEMM1: mid = silu(A@W1T^T) * (A@W3T^T); 128x128 tile, BK=64, single buffer
__global__ __launch_bounds__(256, 2)
void gemm1_bf16(const bf16_t* __restrict__ xr, const bf16_t* __restrict__ xs,
                const bf16_t* __restrict__ w1T, const bf16_t* __restrict__ w3T,
                const bf16_t* __restrict__ ws1T, const bf16_t* __restrict__ ws3T,
                const int* __restrict__ offsets,
                bf16_t* __restrict__ mid_r, bf16_t* __restrict__ mid_s)
{
    const int g  = blockIdx.z;
    const int n0 = blockIdx.x * 128;
    int m0, mEnd;
    const bf16_t *pa, *pw1, *pw3;
    bf16_t* pout;
    if (g < NEXP) {
        int s = offsets[g], e = offsets[g + 1];
        m0 = s + blockIdx.y * 128;
        if (m0 >= e) return;
        mEnd = e;
        pa = xr;
        pw1 = w1T + (size_t)g * DDIM * FDIM;
        pw3 = w3T + (size_t)g * DDIM * FDIM;
        pout = mid_r;
    } else {
        m0 = blockIdx.y * 128;
        mEnd = A_TOK;
        pa = xs; pw1 = ws1T; pw3 = ws3T; pout = mid_s;
    }

    __shared__ __align__(16) bf16_t sA[128 * 64];
    __shared__ __align__(16) bf16_t sB1[128 * 64];
    __shared__ __align__(16) bf16_t sB3[128 * 64];

    const int tid  = threadIdx.x;
    const int lane = tid & 63;
    const int wid  = tid >> 6;
    const int wm   = wid >> 1, wn = wid & 1;
    const int fr   = lane & 15;
    const int fq   = lane >> 4;

    f32x4 acc1[4][4], acc3[4][4];
#pragma unroll
    for (int i = 0; i < 4; ++i)
#pragma unroll
        for (int j = 0; j < 4; ++j) {
            acc1[i][j] = (f32x4){0.f, 0.f, 0.f, 0.f};
            acc3[i][j] = (f32x4){0.f, 0.f, 0.f, 0.f};
        }

    const bf16_t* srcA  = pa  + (size_t)m0 * DDIM;
    const bf16_t* srcB1 = pw1 + (size_t)n0 * DDIM;
    const bf16_t* srcB3 = pw3 + (size_t)n0 * DDIM;

    for (int k0 = 0; k0 < DDIM; k0 += 64) {
        stage_swz(srcA  + k0, DDIM, sA,  tid);
        stage_swz(srcB1 + k0, DDIM, sB1, tid);
        stage_swz(srcB3 + k0, DDIM, sB3, tid);
        __syncthreads();

#pragma unroll
        for (int s = 0; s < 2; ++s) {
            const int kg = s * 4 + fq;
            bf16x8 af[4], b1f[4], b3f[4];
#pragma unroll
            for (int mi = 0; mi < 4; ++mi) {
                int r = wm * 64 + mi * 16 + fr;
                af[mi] = *(const bf16x8*)((const char*)sA + swz_off(r, kg));
            }
#pragma unroll
            for (int ni = 0; ni < 4; ++ni) {
                int r = wn * 64 + ni * 16 + fr;
                b1f[ni] = *(const bf16x8*)((const char*)sB1 + swz_off(r, kg));
                b3f[ni] = *(const bf16x8*)((const char*)sB3 + swz_off(r, kg));
            }
#pragma unroll
            for (int mi = 0; mi < 4; ++mi)
#pragma unroll
                for (int ni = 0; ni < 4; ++ni) {
                    acc1[mi][ni] = __builtin_amdgcn_mfma_f32_16x16x32_bf16(af[mi], b1f[ni], acc1[mi][ni], 0, 0, 0);
                    acc3[mi][ni] = __builtin_amdgcn_mfma_f32_16x16x32_bf16(af[mi], b3f[ni], acc3[mi][ni], 0, 0, 0);
                }
        }
        __syncthreads();
    }

#pragma unroll
    for (int mi = 0; mi < 4; ++mi) {
        int prow_b = m0 + wm * 64 + mi * 16 + fq * 4;
#pragma unroll
        for (int r = 0; r < 4; ++r) {
            int prow = prow_b + r;
            if (prow < mEnd) {
#pragma unroll
                for (int ni = 0; ni < 4; ++ni) {
                    float h1 = acc1[mi][ni][r];
                    float h3 = acc3[mi][ni][r];
                    float vv = h1 / (1.0f + __expf(-h1)) * h3;
                    int col = n0 + wn * 64 + ni * 16 + fr;
                    pout[(size_t)prow * FDIM + col] = (bf16_t)vv;
                }
            }
        }
    }
}

// GEMM2: out = mid @ W2; 128x128 tile, BK=64, single buffer (R3 exact)
template <bool ROUTED>
__global__ __launch_bounds__(256, 2)
void gemm2_bf16(const bf16_t* __restrict__ mid, const bf16_t* __restrict__ w2T,
                const int* __restrict__ perm, const int* __restrict__ offsets,
                float* __restrict__ out)
{
    const int n0 = blockIdx.x * 128;
    int m0, mEnd;
    const bf16_t* pb;
    if (ROUTED) {
        int g = blockIdx.z;
        int s = offsets[g], e = offsets[g + 1];
        m0 = s + blockIdx.y * 128;
        if (m0 >= e) return;
        mEnd = e;
        pb = w2T + (size_t)g * DDIM * FDIM;
    } else {
        m0 = blockIdx.y * 128;
        mEnd = A_TOK;
        pb = w2T;
    }

    __shared__ __align__(16) bf16_t sA[128 * 64];
    __shared__ __align__(16) bf16_t sB[128 * 64];

    const int tid  = threadIdx.x;
    const int lane = tid & 63;
    const int wid  = tid >> 6;
    const int wm   = wid >> 1, wn = wid & 1;
    const int fr   = lane & 15;
    const int fq   = lane >> 4;

    f32x4 acc[4][4];
#pragma unroll
    for (int i = 0; i < 4; ++i)
#pragma unroll
        for (int j = 0; j < 4; ++j)
            acc[i][j] = (f32x4){0.f, 0.f, 0.f, 0.f};

    const bf16_t* srcA = mid + (size_t)m0 * FDIM;
    const bf16_t* srcB = pb  + (size_t)n0 * FDIM;

    for (int k0 = 0; k0 < FDIM; k0 += 64) {
        stage_swz(srcA + k0, FDIM, sA, tid);
        stage_swz(srcB + k0, FDIM, sB, tid);
        __syncthreads();

#pragma unroll
        for (int s = 0; s < 2; ++s) {
            const int kg = s * 4 + fq;
            bf16x8 af[4], bf[4];
#pragma unroll
            for (int mi = 0; mi < 4; ++mi) {
                int r = wm * 64 + mi * 16 + fr;
                af[mi] = *(const bf16x8*)((const char*)sA + swz_off(r, kg));
            }
#pragma unroll
            for (int ni = 0; ni < 4; ++ni) {
                int r = wn * 64 + ni * 16 + fr;
                bf[ni] = *(const bf16x8*)((const char*)sB + swz_off(r, kg));
            }
#pragma unroll
            for (int mi = 0; mi < 4; ++mi)
#pragma unroll
                for (int ni = 0; ni < 4; ++ni)
                    acc[mi][ni] = __builtin_amdgcn_mfma_f32_16x16x32_bf16(af[mi], bf[ni], acc[mi][ni], 0, 0, 0);
        }
        __syncthreads();
    }

#pragma unroll
    for (int mi = 0; mi < 4; ++mi) {
        int prow_b = m0 + wm * 64 + mi * 16 + fq * 4;
#pragma unroll
        for (int r = 0; r < 4; ++r) {
            int prow = prow_b + r;
            if (prow < mEnd) {
                int orow = ROUTED ? perm[prow] : prow;
#pragma unroll
                for (int ni = 0; ni < 4; ++ni) {
                    int col = n0 + wn * 64 + ni * 16 + fr;
                    float vv = acc[mi][ni][r];
                    if (ROUTED)
                        out[(size_t)orow * DDIM + col] += vv;
                    else
                        out[(size_t)orow * DDIM + col] = vv;
                }
            }
        }
    }
}

// ======================= launch =======================
extern "C" void kernel_launch(void* const* d_in, const int* in_sizes, int n_in,
                              void* d_out, int out_size, void* d_ws, size_t ws_size,
                              hipStream_t stream)
{
    const float* x      = (const float*)d_in[0];
    const float* router = (const float*)d_in[1];
    const float* w1     = (const float*)d_in[2];
    const float* w3     = (const float*)d_in[3];
    const float* w2     = (const float*)d_in[4];
    const float* ws1    = (const float*)d_in[5];
    const float* ws3    = (const float*)d_in[6];
    const float* ws2    = (const float*)d_in[7];
    float* out = (float*)d_out;

    char* ws = (char*)d_ws;
    int*   idx_a   = (int*)(ws + 0);
    float* gate_a  = (float*)(ws + 16384);
    int*   offsets = (int*)(ws + 32832);
    int*   perm    = (int*)(ws + 33280);

    bf16_t* xs    = (bf16_t*)(ws + OFF_XS);
    bf16_t* xr    = (bf16_t*)(ws + OFF_XR);
    bf16_t* mid_s = (bf16_t*)(ws + OFF_MIDS);
    bf16_t* mid_r = (bf16_t*)(ws + OFF_MIDR);
    bf16_t* w1T   = (bf16_t*)(ws + OFF_W1T);
    bf16_t* w3T   = (bf16_t*)(ws + OFF_W3T);
    bf16_t* w2T   = (bf16_t*)(ws + OFF_W2T);
    bf16_t* ws1T  = (bf16_t*)(ws + OFF_WS1T);
    bf16_t* ws3T  = (bf16_t*)(ws + OFF_WS3T);
    bf16_t* ws2T  = (bf16_t*)(ws + OFF_WS2T);

    score_kernel<<<A_TOK / 4, 256, 0, stream>>>(x, router, idx_a, gate_a);
    perm_kernel<<<1, 1024, 0, stream>>>(idx_a, offsets, perm);

    prep_x_kernel<<<A_TOK, 256, 0, stream>>>(x, gate_a, perm, xs, xr);
    tconvA_kernel<<<dim3(FDIM / 64, DDIM / 64, 18), 256, 0, stream>>>(
        w1, w3, ws1, ws3, w1T, w3T, ws1T, ws3T);

    gemm1_bf16<<<dim3(FDIM / 128, 32, NEXP + 1), 256, 0, stream>>>(
        xr, xs, w1T, w3T, ws1T, ws3T, offsets, mid_r, mid_s);

    tconvB_kernel<<<dim3(DDIM / 64, FDIM / 64, 9), 256, 0, stream>>>(
        w2, ws2, w2T, ws2T);

    gemm2_bf16<false><<<dim3(DDIM / 128, 32, 1), 256, 0, stream>>>(
        mid_s, ws2T, perm, offsets, out);
    gemm2_bf16<true><<<dim3(DDIM / 128, 32, NEXP), 256, 0, stream>>>(
        mid_r, w2T, perm, offsets, out);
}

// Round 8
// 373.887 us; speedup vs baseline: 1.3392x; 1.0385x over previous
//
#include <hip/hip_runtime.h>
#include <hip/hip_bf16.h>
#include <math.h>

#define A_TOK 4096
#define DDIM  1024
#define NEXP  8
#define FDIM  2816

typedef __bf16 bf16_t;
typedef __bf16 bf16x8 __attribute__((ext_vector_type(8)));
typedef __bf16 bf16x4 __attribute__((ext_vector_type(4)));
typedef __bf16 bf16x2 __attribute__((ext_vector_type(2)));
typedef float  f32x4  __attribute__((ext_vector_type(4)));

// ======================= workspace layout =======================
//   [0,16384)      int   idx_a[4096]
//   [16384,32768)  float gate_a[4096]
//   [32832,32868)  int   offsets[9]
//   [33280,49664)  int   perm[4096]
static constexpr size_t OFF_XS   = 65536;
static constexpr size_t OFF_XR   = OFF_XS   + (size_t)A_TOK * DDIM * 2;
static constexpr size_t OFF_MIDS = OFF_XR   + (size_t)(A_TOK + 128) * DDIM * 2;
static constexpr size_t OFF_MIDR = OFF_MIDS + (size_t)A_TOK * FDIM * 2;
static constexpr size_t OFF_W1T  = OFF_MIDR + (size_t)(A_TOK + 128) * FDIM * 2;
static constexpr size_t OFF_W3T  = OFF_W1T  + (size_t)NEXP * DDIM * FDIM * 2;
static constexpr size_t OFF_W2T  = OFF_W3T  + (size_t)NEXP * DDIM * FDIM * 2;
static constexpr size_t OFF_WS1T = OFF_W2T  + (size_t)NEXP * DDIM * FDIM * 2;
static constexpr size_t OFF_WS3T = OFF_WS1T + (size_t)DDIM * FDIM * 2;
static constexpr size_t OFF_WS2T = OFF_WS3T + (size_t)DDIM * FDIM * 2;
static constexpr size_t WS_NEED  = OFF_WS2T + (size_t)DDIM * FDIM * 2;   // ~209.5 MiB

// Tuning ledger (measured):
//  R3: GEMMs (256,2), BK=64, 8-slot XOR swizzle, single buffer -> gemm1 120.7us,
//      MfmaUtil 34.6, 0 bank conflicts. 787 TF ~= 86% of m97-structure ceiling.
//  R4: BK=32 dbuf + __syncthreads prefetch -> conflicts 8.9e6 + vmcnt(0) drain.
//      REVERTED.
//  R5: XCD remap -> FETCH 292->151MB but 120.7->129.3us (latency-bound).
//      REVERTED.
//  R6: launch_bounds(256,3) -> 84 VGPR, acc spilled (WRITE 45->93MB), 232us.
//      REVERTED. Keep (256,2).
//  R7: tconv u32-packed rewrite -> neutral (tconv is BW-floor). Total 388.
//  R8: merged single-writer gemm2 (this round).

// ======================= router: scores =======================
__global__ __launch_bounds__(256)
void score_kernel(const float* __restrict__ x,
                  const float* __restrict__ router,
                  int* __restrict__ idx_a,
                  float* __restrict__ gate_a)
{
    __shared__ float rT[NEXP][DDIM];
    const int tid = threadIdx.x;
    for (int i = tid; i < DDIM * NEXP; i += 256)
        rT[i & 7][i >> 3] = router[i];
    __syncthreads();

    const int wid = tid >> 6, lane = tid & 63;
    const int t = blockIdx.x * 4 + wid;
    const float* xr = x + (size_t)t * DDIM;

    double s[NEXP];
#pragma unroll
    for (int e = 0; e < NEXP; ++e) s[e] = 0.0;
#pragma unroll
    for (int i = 0; i < DDIM / 64; ++i) {
        int d = i * 64 + lane;
        float xv = xr[d];
#pragma unroll
        for (int e = 0; e < NEXP; ++e)
            s[e] += (double)xv * (double)rT[e][d];
    }
#pragma unroll
    for (int e = 0; e < NEXP; ++e) {
#pragma unroll
        for (int off = 32; off > 0; off >>= 1)
            s[e] += __shfl_xor(s[e], off);
    }
    if (lane == 0) {
        int best = 0; double bv = s[0];
#pragma unroll
        for (int e = 1; e < NEXP; ++e)
            if (s[e] > bv) { bv = s[e]; best = e; }
        idx_a[t] = best;
        gate_a[t] = 1.0f / (1.0f + expf(-(float)bv));
    }
}

// ======================= fused count + scan + scatter =======================
__global__ __launch_bounds__(1024)
void perm_kernel(const int* __restrict__ idx_a,
                 int* __restrict__ offsets,
                 int* __restrict__ perm)
{
    __shared__ int cnt[NEXP];
    __shared__ int base[NEXP];
    const int tid = threadIdx.x;
    if (tid < NEXP) cnt[tid] = 0;
    __syncthreads();

    int e[4];
#pragma unroll
    for (int j = 0; j < 4; ++j) {
        e[j] = idx_a[j * 1024 + tid];
        atomicAdd(&cnt[e[j]], 1);
    }
    __syncthreads();
    if (tid == 0) {
        int acc = 0;
#pragma unroll
        for (int k = 0; k < NEXP; ++k) {
            base[k] = acc; offsets[k] = acc; acc += cnt[k];
        }
        offsets[NEXP] = acc;
    }
    __syncthreads();
#pragma unroll
    for (int j = 0; j < 4; ++j) {
        int t = j * 1024 + tid;
        int pos = atomicAdd(&base[e[j]], 1);
        perm[pos] = t;
    }
}

// ======================= prep kernels =======================
__global__ void prep_x_kernel(const float* __restrict__ x,
                              const float* __restrict__ gate_a,
                              const int* __restrict__ perm,
                              bf16_t* __restrict__ xs,
                              bf16_t* __restrict__ xr)
{
    const int p = blockIdx.x;
    const int d = threadIdx.x * 4;
    float4 v = *(const float4*)(x + (size_t)p * DDIM + d);
    bf16x4 o;
    o[0] = (bf16_t)v.x; o[1] = (bf16_t)v.y; o[2] = (bf16_t)v.z; o[3] = (bf16_t)v.w;
    *(bf16x4*)(xs + (size_t)p * DDIM + d) = o;

    const int tok = perm[p];
    const float g = gate_a[tok];
    float4 w = *(const float4*)(x + (size_t)tok * DDIM + d);
    bf16x4 o2;
    o2[0] = (bf16_t)(w.x * g); o2[1] = (bf16_t)(w.y * g);
    o2[2] = (bf16_t)(w.z * g); o2[3] = (bf16_t)(w.w * g);
    *(bf16x4*)(xr + (size_t)p * DDIM + d) = o2;
}

// pack two fp32 rows' element into one u32 of 2 bf16 (low = first row)
__device__ __forceinline__ unsigned pk2(float a, float b)
{
    union { bf16x2 v; unsigned u; } x;
    x.v[0] = (bf16_t)a; x.v[1] = (bf16_t)b;
    return x.u;
}

// transpose+convert core: src [R][C] fp32 -> dst [C][R] bf16, one 64x64 tile.
__device__ __forceinline__ void tconv_tile(const float* __restrict__ src,
                                           bf16_t* __restrict__ dst,
                                           int R, int C, int r0, int c0)
{
    __shared__ unsigned t2[64][33];
    const int tid = threadIdx.x;
    const int cl = (tid & 15) * 4;
    const int rh = tid >> 4;
#pragma unroll
    for (int i = 0; i < 2; ++i) {
        const int r = rh * 2 + i * 32;
        const float* s0 = src + (size_t)(r0 + r) * C + c0 + cl;
        float4 v0 = *(const float4*)s0;
        float4 v1 = *(const float4*)(s0 + C);
        t2[cl + 0][rh + i * 16] = pk2(v0.x, v1.x);
        t2[cl + 1][rh + i * 16] = pk2(v0.y, v1.y);
        t2[cl + 2][rh + i * 16] = pk2(v0.z, v1.z);
        t2[cl + 3][rh + i * 16] = pk2(v0.w, v1.w);
    }
    __syncthreads();
    const int c2 = tid >> 3;
    const int rq = (tid & 7) * 4;
#pragma unroll
    for (int i = 0; i < 2; ++i) {
        const int c = c2 + i * 32;
        uint4 vv;
        vv.x = t2[c][rq + 0];
        vv.y = t2[c][rq + 1];
        vv.z = t2[c][rq + 2];
        vv.w = t2[c][rq + 3];
        *(uint4*)(dst + (size_t)(c0 + c) * R + r0 + rq * 2) = vv;
    }
}

__global__ void tconvA_kernel(const float* __restrict__ w1, const float* __restrict__ w3,
                              const float* __restrict__ ws1, const float* __restrict__ ws3,
                              bf16_t* __restrict__ w1T, bf16_t* __restrict__ w3T,
                              bf16_t* __restrict__ ws1T, bf16_t* __restrict__ ws3T)
{
    const int z = blockIdx.z;
    const size_t ms = (size_t)DDIM * FDIM;
    const float* src; bf16_t* dst;
    if (z < 8)       { src = w1 + (size_t)z * ms;       dst = w1T + (size_t)z * ms; }
    else if (z < 16) { src = w3 + (size_t)(z - 8) * ms; dst = w3T + (size_t)(z - 8) * ms; }
    else if (z == 16){ src = ws1;                        dst = ws1T; }
    else             { src = ws3;                        dst = ws3T; }
    tconv_tile(src, dst, DDIM, FDIM, blockIdx.y * 64, blockIdx.x * 64);
}

__global__ void tconvB_kernel(const float* __restrict__ w2, const float* __restrict__ ws2,
                              bf16_t* __restrict__ w2T, bf16_t* __restrict__ ws2T)
{
    const int z = blockIdx.z;
    const size_t ms = (size_t)DDIM * FDIM;
    const float* src; bf16_t* dst;
    if (z < 8) { src = w2 + (size_t)z * ms; dst = w2T + (size_t)z * ms; }
    else       { src = ws2;                  dst = ws2T; }
    tconv_tile(src, dst, FDIM, DDIM, blockIdx.y * 64, blockIdx.x * 64);
}

// ======================= bf16 GEMM machinery =======================
__device__ __forceinline__ void glds16(const bf16_t* g, bf16_t* l)
{
    __builtin_amdgcn_global_load_lds(
        (const __attribute__((address_space(1))) void*)g,
        (__attribute__((address_space(3))) void*)l, 16, 0, 0);
}

// stage 128 rows x 64 bf16 (128B/row), XOR-swizzled on 16B slots (8 slots/row):
// LDS[row][slot] = global[row][slot ^ (row&7)]   -- measured 0 bank conflicts
__device__ __forceinline__ void stage_swz(const bf16_t* __restrict__ src,
                                          size_t stride, bf16_t* lds, int tid)
{
#pragma unroll
    for (int i = 0; i < 4; ++i) {
        int o = i * 256 + tid;
        int row = o >> 3;
        int slot = o & 7;
        int srcSlot = slot ^ (row & 7);
        glds16(src + (size_t)row * stride + srcSlot * 8, lds + (size_t)o * 8);
    }
}

// gathered variant: per-thread row base pointers (4 rows/thread), same swizzle.
// rowPtr[i] corresponds to LDS row (tid>>3) + 32*i.
__device__ __forceinline__ void stage_swz_gather(const bf16_t* const* rowPtr,
                                                 int k0, bf16_t* lds, int tid)
{
#pragma unroll
    for (int i = 0; i < 4; ++i) {
        int o = i * 256 + tid;
        int row = o >> 3;
        int slot = o & 7;
        int srcSlot = slot ^ (row & 7);
        glds16(rowPtr[i] + k0 + srcSlot * 8, lds + (size_t)o * 8);
    }
}

__device__ __forceinline__ int swz_off(int row, int g16)
{
    return row * 128 + ((g16 ^ (row & 7)) << 4);
}

// GEMM1: mid = silu(A@W1T^T) * (A@W3T^T); 128x128 tile, BK=64, single buffer
__global__ __launch_bounds__(256, 2)
void gemm1_bf16(const bf16_t* __restrict__ xr, const bf16_t* __restrict__ xs,
                const bf16_t* __restrict__ w1T, const bf16_t* __restrict__ w3T,
                const bf16_t* __restrict__ ws1T, const bf16_t* __restrict__ ws3T,
                const int* __restrict__ offsets,
                bf16_t* __restrict__ mid_r, bf16_t* __restrict__ mid_s)
{
    const int g  = blockIdx.z;
    const int n0 = blockIdx.x * 128;
    int m0, mEnd;
    const bf16_t *pa, *pw1, *pw3;
    bf16_t* pout;
    if (g < NEXP) {
        int s = offsets[g], e = offsets[g + 1];
        m0 = s + blockIdx.y * 128;
        if (m0 >= e) return;
        mEnd = e;
        pa = xr;
        pw1 = w1T + (size_t)g * DDIM * FDIM;
        pw3 = w3T + (size_t)g * DDIM * FDIM;
        pout = mid_r;
    } else {
        m0 = blockIdx.y * 128;
        mEnd = A_TOK;
        pa = xs; pw1 = ws1T; pw3 = ws3T; pout = mid_s;
    }

    __shared__ __align__(16) bf16_t sA[128 * 64];
    __shared__ __align__(16) bf16_t sB1[128 * 64];
    __shared__ __align__(16) bf16_t sB3[128 * 64];

    const int tid  = threadIdx.x;
    const int lane = tid & 63;
    const int wid  = tid >> 6;
    const int wm   = wid >> 1, wn = wid & 1;
    const int fr   = lane & 15;
    const int fq   = lane >> 4;

    f32x4 acc1[4][4], acc3[4][4];
#pragma unroll
    for (int i = 0; i < 4; ++i)
#pragma unroll
        for (int j = 0; j < 4; ++j) {
            acc1[i][j] = (f32x4){0.f, 0.f, 0.f, 0.f};
            acc3[i][j] = (f32x4){0.f, 0.f, 0.f, 0.f};
        }

    const bf16_t* srcA  = pa  + (size_t)m0 * DDIM;
    const bf16_t* srcB1 = pw1 + (size_t)n0 * DDIM;
    const bf16_t* srcB3 = pw3 + (size_t)n0 * DDIM;

    for (int k0 = 0; k0 < DDIM; k0 += 64) {
        stage_swz(srcA  + k0, DDIM, sA,  tid);
        stage_swz(srcB1 + k0, DDIM, sB1, tid);
        stage_swz(srcB3 + k0, DDIM, sB3, tid);
        __syncthreads();

#pragma unroll
        for (int s = 0; s < 2; ++s) {
            const int kg = s * 4 + fq;
            bf16x8 af[4], b1f[4], b3f[4];
#pragma unroll
            for (int mi = 0; mi < 4; ++mi) {
                int r = wm * 64 + mi * 16 + fr;
                af[mi] = *(const bf16x8*)((const char*)sA + swz_off(r, kg));
            }
#pragma unroll
            for (int ni = 0; ni < 4; ++ni) {
                int r = wn * 64 + ni * 16 + fr;
                b1f[ni] = *(const bf16x8*)((const char*)sB1 + swz_off(r, kg));
                b3f[ni] = *(const bf16x8*)((const char*)sB3 + swz_off(r, kg));
            }
#pragma unroll
            for (int mi = 0; mi < 4; ++mi)
#pragma unroll
                for (int ni = 0; ni < 4; ++ni) {
                    acc1[mi][ni] = __builtin_amdgcn_mfma_f32_16x16x32_bf16(af[mi], b1f[ni], acc1[mi][ni], 0, 0, 0);
                    acc3[mi][ni] = __builtin_amdgcn_mfma_f32_16x16x32_bf16(af[mi], b3f[ni], acc3[mi][ni], 0, 0, 0);
                }
        }
        __syncthreads();
    }

#pragma unroll
    for (int mi = 0; mi < 4; ++mi) {
        int prow_b = m0 + wm * 64 + mi * 16 + fq * 4;
#pragma unroll
        for (int r = 0; r < 4; ++r) {
            int prow = prow_b + r;
            if (prow < mEnd) {
#pragma unroll
                for (int ni = 0; ni < 4; ++ni) {
                    float h1 = acc1[mi][ni][r];
                    float h3 = acc3[mi][ni][r];
                    float vv = h1 / (1.0f + __expf(-h1)) * h3;
                    int col = n0 + wn * 64 + ni * 16 + fr;
                    pout[(size_t)prow * FDIM + col] = (bf16_t)vv;
                }
            }
        }
    }
}

// GEMM2 merged (single-writer): for expert e's rows,
//   out[perm[row]] = mid_r[row] @ w2T[e]  +  mid_s[perm[row]] @ ws2T
// Two K-loops into ONE accumulator; one plain fp32 store per element.
// mid_s rows are gathered via per-lane global_load_lds source addresses (m173).
__global__ __launch_bounds__(256, 2)
void gemm2m_bf16(const bf16_t* __restrict__ mid_r, const bf16_t* __restrict__ mid_s,
                 const bf16_t* __restrict__ w2T, const bf16_t* __restrict__ ws2T,
                 const int* __restrict__ perm, const int* __restrict__ offsets,
                 float* __restrict__ out)
{
    const int e  = blockIdx.z;
    const int n0 = blockIdx.x * 128;
    const int s  = offsets[e], eEnd = offsets[e + 1];
    const int m0 = s + blockIdx.y * 128;
    if (m0 >= eEnd) return;
    const int mEnd = eEnd;

    __shared__ __align__(16) bf16_t sA[128 * 64];
    __shared__ __align__(16) bf16_t sB[128 * 64];

    const int tid  = threadIdx.x;
    const int lane = tid & 63;
    const int wid  = tid >> 6;
    const int wm   = wid >> 1, wn = wid & 1;
    const int fr   = lane & 15;
    const int fq   = lane >> 4;

    f32x4 acc[4][4];
#pragma unroll
    for (int i = 0; i < 4; ++i)
#pragma unroll
        for (int j = 0; j < 4; ++j)
            acc[i][j] = (f32x4){0.f, 0.f, 0.f, 0.f};

    // per-thread gathered row pointers for the shared pass
    const int baseRow = tid >> 3;
    const bf16_t* rowPtr[4];
#pragma unroll
    for (int i = 0; i < 4; ++i) {
        int rr = m0 + baseRow + 32 * i;
        int tok = perm[rr < mEnd ? rr : m0];   // clamp: garbage rows masked at store
        rowPtr[i] = mid_s + (size_t)tok * FDIM;
    }

#define G2M_COMPUTE() do {                                                    \
        _Pragma("unroll")                                                     \
        for (int ss = 0; ss < 2; ++ss) {                                      \
            const int kg = ss * 4 + fq;                                       \
            bf16x8 af[4], bf[4];                                              \
            _Pragma("unroll")                                                 \
            for (int mi = 0; mi < 4; ++mi) {                                  \
                int r = wm * 64 + mi * 16 + fr;                               \
                af[mi] = *(const bf16x8*)((const char*)sA + swz_off(r, kg));  \
            }                                                                 \
            _Pragma("unroll")                                                 \
            for (int ni = 0; ni < 4; ++ni) {                                  \
                int r = wn * 64 + ni * 16 + fr;                               \
                bf[ni] = *(const bf16x8*)((const char*)sB + swz_off(r, kg));  \
            }                                                                 \
            _Pragma("unroll")                                                 \
            for (int mi = 0; mi < 4; ++mi)                                    \
                _Pragma("unroll")                                             \
                for (int ni = 0; ni < 4; ++ni)                                \
                    acc[mi][ni] = __builtin_amdgcn_mfma_f32_16x16x32_bf16(    \
                        af[mi], bf[ni], acc[mi][ni], 0, 0, 0);                \
        }                                                                     \
    } while (0)

    // pass 1: routed contribution  (A = mid_r rows m0.., B = w2T[e])
    {
        const bf16_t* srcA = mid_r + (size_t)m0 * FDIM;
        const bf16_t* srcB = w2T + (size_t)e * DDIM * FDIM + (size_t)n0 * FDIM;
        for (int k0 = 0; k0 < FDIM; k0 += 64) {
            stage_swz(srcA + k0, FDIM, sA, tid);
            stage_swz(srcB + k0, FDIM, sB, tid);
            __syncthreads();
            G2M_COMPUTE();
            __syncthreads();
        }
    }
    // pass 2: shared contribution  (A = mid_s gathered rows, B = ws2T)
    {
        const bf16_t* srcB = ws2T + (size_t)n0 * FDIM;
        for (int k0 = 0; k0 < FDIM; k0 += 64) {
            stage_swz_gather(rowPtr, k0, sA, tid);
            stage_swz(srcB + k0, FDIM, sB, tid);
            __syncthreads();
            G2M_COMPUTE();
            __syncthreads();
        }
    }
#undef G2M_COMPUTE

#pragma unroll
    for (int mi = 0; mi < 4; ++mi) {
        int prow_b = m0 + wm * 64 + mi * 16 + fq * 4;
#pragma unroll
        for (int r = 0; r < 4; ++r) {
            int prow = prow_b + r;
            if (prow < mEnd) {
                int orow = perm[prow];
#pragma unroll
                for (int ni = 0; ni < 4; ++ni) {
                    int col = n0 + wn * 64 + ni * 16 + fr;
                    out[(size_t)orow * DDIM + col] = acc[mi][ni][r];
                }
            }
        }
    }
}

// ======================= launch =======================
extern "C" void kernel_launch(void* const* d_in, const int* in_sizes, int n_in,
                              void* d_out, int out_size, void* d_ws, size_t ws_size,
                              hipStream_t stream)
{
    const float* x      = (const float*)d_in[0];
    const float* router = (const float*)d_in[1];
    const float* w1     = (const float*)d_in[2];
    const float* w3     = (const float*)d_in[3];
    const float* w2     = (const float*)d_in[4];
    const float* ws1    = (const float*)d_in[5];
    const float* ws3    = (const float*)d_in[6];
    const float* ws2    = (const float*)d_in[7];
    float* out = (float*)d_out;

    char* ws = (char*)d_ws;
    int*   idx_a   = (int*)(ws + 0);
    float* gate_a  = (float*)(ws + 16384);
    int*   offsets = (int*)(ws + 32832);
    int*   perm    = (int*)(ws + 33280);

    bf16_t* xs    = (bf16_t*)(ws + OFF_XS);
    bf16_t* xr    = (bf16_t*)(ws + OFF_XR);
    bf16_t* mid_s = (bf16_t*)(ws + OFF_MIDS);
    bf16_t* mid_r = (bf16_t*)(ws + OFF_MIDR);
    bf16_t* w1T   = (bf16_t*)(ws + OFF_W1T);
    bf16_t* w3T   = (bf16_t*)(ws + OFF_W3T);
    bf16_t* w2T   = (bf16_t*)(ws + OFF_W2T);
    bf16_t* ws1T  = (bf16_t*)(ws + OFF_WS1T);
    bf16_t* ws3T  = (bf16_t*)(ws + OFF_WS3T);
    bf16_t* ws2T  = (bf16_t*)(ws + OFF_WS2T);

    score_kernel<<<A_TOK / 4, 256, 0, stream>>>(x, router, idx_a, gate_a);
    perm_kernel<<<1, 1024, 0, stream>>>(idx_a, offsets, perm);

    prep_x_kernel<<<A_TOK, 256, 0, stream>>>(x, gate_a, perm, xs, xr);
    tconvA_kernel<<<dim3(FDIM / 64, DDIM / 64, 18), 256, 0, stream>>>(
        w1, w3, ws1, ws3, w1T, w3T, ws1T, ws3T);

    gemm1_bf16<<<dim3(FDIM / 128, 32, NEXP + 1), 256, 0, stream>>>(
        xr, xs, w1T, w3T, ws1T, ws3T, offsets, mid_r, mid_s);

    tconvB_kernel<<<dim3(DDIM / 64, FDIM / 64, 9), 256, 0, stream>>>(
        w2, ws2, w2T, ws2T);

    gemm2m_bf16<<<dim3(DDIM / 128, 32, NEXP), 256, 0, stream>>>(
        mid_r, mid_s, w2T, ws2T, perm, offsets, out);
}

// Round 9
// 344.609 us; speedup vs baseline: 1.4529x; 1.0850x over previous
//
#include <hip/hip_runtime.h>
#include <hip/hip_bf16.h>
#include <math.h>

#define A_TOK 4096
#define DDIM  1024
#define NEXP  8
#define FDIM  2816

typedef __bf16 bf16_t;
typedef __bf16 bf16x8 __attribute__((ext_vector_type(8)));
typedef __bf16 bf16x4 __attribute__((ext_vector_type(4)));
typedef __bf16 bf16x2 __attribute__((ext_vector_type(2)));
typedef float  f32x4  __attribute__((ext_vector_type(4)));

// ======================= workspace layout =======================
//   [0,16384)      int   idx_a[4096]
//   [16384,32768)  float gate_a[4096]
//   [32832,32868)  int   offsets[9]
//   [33280,49664)  int   perm[4096]
static constexpr size_t OFF_XS   = 65536;
static constexpr size_t OFF_XR   = OFF_XS   + (size_t)A_TOK * DDIM * 2;
static constexpr size_t OFF_MIDS = OFF_XR   + (size_t)(A_TOK + 128) * DDIM * 2;
static constexpr size_t OFF_MIDR = OFF_MIDS + (size_t)A_TOK * FDIM * 2;
static constexpr size_t OFF_W1T  = OFF_MIDR + (size_t)(A_TOK + 128) * FDIM * 2;
static constexpr size_t OFF_W3T  = OFF_W1T  + (size_t)NEXP * DDIM * FDIM * 2;
static constexpr size_t OFF_W2T  = OFF_W3T  + (size_t)NEXP * DDIM * FDIM * 2;
static constexpr size_t OFF_WS1T = OFF_W2T  + (size_t)NEXP * DDIM * FDIM * 2;
static constexpr size_t OFF_WS3T = OFF_WS1T + (size_t)DDIM * FDIM * 2;
static constexpr size_t OFF_WS2T = OFF_WS3T + (size_t)DDIM * FDIM * 2;
static constexpr size_t WS_NEED  = OFF_WS2T + (size_t)DDIM * FDIM * 2;   // ~209.5 MiB

// Tuning ledger (measured):
//  R3: GEMMs (256,2), BK=64, 8-slot XOR swizzle, single buffer -> gemm1 120.7us,
//      MfmaUtil 34.6, 0 bank conflicts. 787 TF ~= 86% of m97-structure ceiling.
//  R4: BK=32 dbuf + __syncthreads prefetch -> conflicts 8.9e6 + vmcnt(0) drain. REVERTED.
//  R5: XCD remap -> FETCH 292->151MB but slower (latency-bound). REVERTED.
//  R6: launch_bounds(256,3) on 64-VGPR-acc kernel -> spills, 232us. REVERTED.
//  R7: tconv u32-packed rewrite -> neutral (BW-floor). Total 388.
//  R8: merged single-writer gemm2 -> WRITE 50->16MB ok, but 256 active blocks
//      = 1 block/CU -> 166us @ 9% occupancy. Fusion sound, grid too coarse.
//  R9: gemm2m BN 128->64 -> 512 active blocks = 2/CU (this round).

// ======================= router: scores =======================
__global__ __launch_bounds__(256)
void score_kernel(const float* __restrict__ x,
                  const float* __restrict__ router,
                  int* __restrict__ idx_a,
                  float* __restrict__ gate_a)
{
    __shared__ float rT[NEXP][DDIM];
    const int tid = threadIdx.x;
    for (int i = tid; i < DDIM * NEXP; i += 256)
        rT[i & 7][i >> 3] = router[i];
    __syncthreads();

    const int wid = tid >> 6, lane = tid & 63;
    const int t = blockIdx.x * 4 + wid;
    const float* xr = x + (size_t)t * DDIM;

    double s[NEXP];
#pragma unroll
    for (int e = 0; e < NEXP; ++e) s[e] = 0.0;
#pragma unroll
    for (int i = 0; i < DDIM / 64; ++i) {
        int d = i * 64 + lane;
        float xv = xr[d];
#pragma unroll
        for (int e = 0; e < NEXP; ++e)
            s[e] += (double)xv * (double)rT[e][d];
    }
#pragma unroll
    for (int e = 0; e < NEXP; ++e) {
#pragma unroll
        for (int off = 32; off > 0; off >>= 1)
            s[e] += __shfl_xor(s[e], off);
    }
    if (lane == 0) {
        int best = 0; double bv = s[0];
#pragma unroll
        for (int e = 1; e < NEXP; ++e)
            if (s[e] > bv) { bv = s[e]; best = e; }
        idx_a[t] = best;
        gate_a[t] = 1.0f / (1.0f + expf(-(float)bv));
    }
}

// ======================= fused count + scan + scatter =======================
__global__ __launch_bounds__(1024)
void perm_kernel(const int* __restrict__ idx_a,
                 int* __restrict__ offsets,
                 int* __restrict__ perm)
{
    __shared__ int cnt[NEXP];
    __shared__ int base[NEXP];
    const int tid = threadIdx.x;
    if (tid < NEXP) cnt[tid] = 0;
    __syncthreads();

    int e[4];
#pragma unroll
    for (int j = 0; j < 4; ++j) {
        e[j] = idx_a[j * 1024 + tid];
        atomicAdd(&cnt[e[j]], 1);
    }
    __syncthreads();
    if (tid == 0) {
        int acc = 0;
#pragma unroll
        for (int k = 0; k < NEXP; ++k) {
            base[k] = acc; offsets[k] = acc; acc += cnt[k];
        }
        offsets[NEXP] = acc;
    }
    __syncthreads();
#pragma unroll
    for (int j = 0; j < 4; ++j) {
        int t = j * 1024 + tid;
        int pos = atomicAdd(&base[e[j]], 1);
        perm[pos] = t;
    }
}

// ======================= prep kernels =======================
__global__ void prep_x_kernel(const float* __restrict__ x,
                              const float* __restrict__ gate_a,
                              const int* __restrict__ perm,
                              bf16_t* __restrict__ xs,
                              bf16_t* __restrict__ xr)
{
    const int p = blockIdx.x;
    const int d = threadIdx.x * 4;
    float4 v = *(const float4*)(x + (size_t)p * DDIM + d);
    bf16x4 o;
    o[0] = (bf16_t)v.x; o[1] = (bf16_t)v.y; o[2] = (bf16_t)v.z; o[3] = (bf16_t)v.w;
    *(bf16x4*)(xs + (size_t)p * DDIM + d) = o;

    const int tok = perm[p];
    const float g = gate_a[tok];
    float4 w = *(const float4*)(x + (size_t)tok * DDIM + d);
    bf16x4 o2;
    o2[0] = (bf16_t)(w.x * g); o2[1] = (bf16_t)(w.y * g);
    o2[2] = (bf16_t)(w.z * g); o2[3] = (bf16_t)(w.w * g);
    *(bf16x4*)(xr + (size_t)p * DDIM + d) = o2;
}

// pack two fp32 rows' element into one u32 of 2 bf16 (low = first row)
__device__ __forceinline__ unsigned pk2(float a, float b)
{
    union { bf16x2 v; unsigned u; } x;
    x.v[0] = (bf16_t)a; x.v[1] = (bf16_t)b;
    return x.u;
}

// transpose+convert core: src [R][C] fp32 -> dst [C][R] bf16, one 64x64 tile.
__device__ __forceinline__ void tconv_tile(const float* __restrict__ src,
                                           bf16_t* __restrict__ dst,
                                           int R, int C, int r0, int c0)
{
    __shared__ unsigned t2[64][33];
    const int tid = threadIdx.x;
    const int cl = (tid & 15) * 4;
    const int rh = tid >> 4;
#pragma unroll
    for (int i = 0; i < 2; ++i) {
        const int r = rh * 2 + i * 32;
        const float* s0 = src + (size_t)(r0 + r) * C + c0 + cl;
        float4 v0 = *(const float4*)s0;
        float4 v1 = *(const float4*)(s0 + C);
        t2[cl + 0][rh + i * 16] = pk2(v0.x, v1.x);
        t2[cl + 1][rh + i * 16] = pk2(v0.y, v1.y);
        t2[cl + 2][rh + i * 16] = pk2(v0.z, v1.z);
        t2[cl + 3][rh + i * 16] = pk2(v0.w, v1.w);
    }
    __syncthreads();
    const int c2 = tid >> 3;
    const int rq = (tid & 7) * 4;
#pragma unroll
    for (int i = 0; i < 2; ++i) {
        const int c = c2 + i * 32;
        uint4 vv;
        vv.x = t2[c][rq + 0];
        vv.y = t2[c][rq + 1];
        vv.z = t2[c][rq + 2];
        vv.w = t2[c][rq + 3];
        *(uint4*)(dst + (size_t)(c0 + c) * R + r0 + rq * 2) = vv;
    }
}

__global__ void tconvA_kernel(const float* __restrict__ w1, const float* __restrict__ w3,
                              const float* __restrict__ ws1, const float* __restrict__ ws3,
                              bf16_t* __restrict__ w1T, bf16_t* __restrict__ w3T,
                              bf16_t* __restrict__ ws1T, bf16_t* __restrict__ ws3T)
{
    const int z = blockIdx.z;
    const size_t ms = (size_t)DDIM * FDIM;
    const float* src; bf16_t* dst;
    if (z < 8)       { src = w1 + (size_t)z * ms;       dst = w1T + (size_t)z * ms; }
    else if (z < 16) { src = w3 + (size_t)(z - 8) * ms; dst = w3T + (size_t)(z - 8) * ms; }
    else if (z == 16){ src = ws1;                        dst = ws1T; }
    else             { src = ws3;                        dst = ws3T; }
    tconv_tile(src, dst, DDIM, FDIM, blockIdx.y * 64, blockIdx.x * 64);
}

__global__ void tconvB_kernel(const float* __restrict__ w2, const float* __restrict__ ws2,
                              bf16_t* __restrict__ w2T, bf16_t* __restrict__ ws2T)
{
    const int z = blockIdx.z;
    const size_t ms = (size_t)DDIM * FDIM;
    const float* src; bf16_t* dst;
    if (z < 8) { src = w2 + (size_t)z * ms; dst = w2T + (size_t)z * ms; }
    else       { src = ws2;                  dst = ws2T; }
    tconv_tile(src, dst, FDIM, DDIM, blockIdx.y * 64, blockIdx.x * 64);
}

// ======================= bf16 GEMM machinery =======================
__device__ __forceinline__ void glds16(const bf16_t* g, bf16_t* l)
{
    __builtin_amdgcn_global_load_lds(
        (const __attribute__((address_space(1))) void*)g,
        (__attribute__((address_space(3))) void*)l, 16, 0, 0);
}

// stage 128 rows x 64 bf16 (128B/row), XOR-swizzled on 16B slots (8 slots/row):
// LDS[row][slot] = global[row][slot ^ (row&7)]   -- measured 0 bank conflicts
__device__ __forceinline__ void stage_swz(const bf16_t* __restrict__ src,
                                          size_t stride, bf16_t* lds, int tid)
{
#pragma unroll
    for (int i = 0; i < 4; ++i) {
        int o = i * 256 + tid;
        int row = o >> 3;
        int slot = o & 7;
        int srcSlot = slot ^ (row & 7);
        glds16(src + (size_t)row * stride + srcSlot * 8, lds + (size_t)o * 8);
    }
}

// 64-row variant (B tile for gemm2m)
__device__ __forceinline__ void stage_swz64(const bf16_t* __restrict__ src,
                                            size_t stride, bf16_t* lds, int tid)
{
#pragma unroll
    for (int i = 0; i < 2; ++i) {
        int o = i * 256 + tid;          // 0..511
        int row = o >> 3;               // 0..63
        int slot = o & 7;
        int srcSlot = slot ^ (row & 7);
        glds16(src + (size_t)row * stride + srcSlot * 8, lds + (size_t)o * 8);
    }
}

// gathered variant: per-thread row base pointers (4 rows/thread), same swizzle.
// rowPtr[i] corresponds to LDS row (tid>>3) + 32*i.
__device__ __forceinline__ void stage_swz_gather(const bf16_t* const* rowPtr,
                                                 int k0, bf16_t* lds, int tid)
{
#pragma unroll
    for (int i = 0; i < 4; ++i) {
        int o = i * 256 + tid;
        int row = o >> 3;
        int slot = o & 7;
        int srcSlot = slot ^ (row & 7);
        glds16(rowPtr[i] + k0 + srcSlot * 8, lds + (size_t)o * 8);
    }
}

__device__ __forceinline__ int swz_off(int row, int g16)
{
    return row * 128 + ((g16 ^ (row & 7)) << 4);
}

// GEMM1: mid = silu(A@W1T^T) * (A@W3T^T); 128x128 tile, BK=64, single buffer
__global__ __launch_bounds__(256, 2)
void gemm1_bf16(const bf16_t* __restrict__ xr, const bf16_t* __restrict__ xs,
                const bf16_t* __restrict__ w1T, const bf16_t* __restrict__ w3T,
                const bf16_t* __restrict__ ws1T, const bf16_t* __restrict__ ws3T,
                const int* __restrict__ offsets,
                bf16_t* __restrict__ mid_r, bf16_t* __restrict__ mid_s)
{
    const int g  = blockIdx.z;
    const int n0 = blockIdx.x * 128;
    int m0, mEnd;
    const bf16_t *pa, *pw1, *pw3;
    bf16_t* pout;
    if (g < NEXP) {
        int s = offsets[g], e = offsets[g + 1];
        m0 = s + blockIdx.y * 128;
        if (m0 >= e) return;
        mEnd = e;
        pa = xr;
        pw1 = w1T + (size_t)g * DDIM * FDIM;
        pw3 = w3T + (size_t)g * DDIM * FDIM;
        pout = mid_r;
    } else {
        m0 = blockIdx.y * 128;
        mEnd = A_TOK;
        pa = xs; pw1 = ws1T; pw3 = ws3T; pout = mid_s;
    }

    __shared__ __align__(16) bf16_t sA[128 * 64];
    __shared__ __align__(16) bf16_t sB1[128 * 64];
    __shared__ __align__(16) bf16_t sB3[128 * 64];

    const int tid  = threadIdx.x;
    const int lane = tid & 63;
    const int wid  = tid >> 6;
    const int wm   = wid >> 1, wn = wid & 1;
    const int fr   = lane & 15;
    const int fq   = lane >> 4;

    f32x4 acc1[4][4], acc3[4][4];
#pragma unroll
    for (int i = 0; i < 4; ++i)
#pragma unroll
        for (int j = 0; j < 4; ++j) {
            acc1[i][j] = (f32x4){0.f, 0.f, 0.f, 0.f};
            acc3[i][j] = (f32x4){0.f, 0.f, 0.f, 0.f};
        }

    const bf16_t* srcA  = pa  + (size_t)m0 * DDIM;
    const bf16_t* srcB1 = pw1 + (size_t)n0 * DDIM;
    const bf16_t* srcB3 = pw3 + (size_t)n0 * DDIM;

    for (int k0 = 0; k0 < DDIM; k0 += 64) {
        stage_swz(srcA  + k0, DDIM, sA,  tid);
        stage_swz(srcB1 + k0, DDIM, sB1, tid);
        stage_swz(srcB3 + k0, DDIM, sB3, tid);
        __syncthreads();

#pragma unroll
        for (int s = 0; s < 2; ++s) {
            const int kg = s * 4 + fq;
            bf16x8 af[4], b1f[4], b3f[4];
#pragma unroll
            for (int mi = 0; mi < 4; ++mi) {
                int r = wm * 64 + mi * 16 + fr;
                af[mi] = *(const bf16x8*)((const char*)sA + swz_off(r, kg));
            }
#pragma unroll
            for (int ni = 0; ni < 4; ++ni) {
                int r = wn * 64 + ni * 16 + fr;
                b1f[ni] = *(const bf16x8*)((const char*)sB1 + swz_off(r, kg));
                b3f[ni] = *(const bf16x8*)((const char*)sB3 + swz_off(r, kg));
            }
#pragma unroll
            for (int mi = 0; mi < 4; ++mi)
#pragma unroll
                for (int ni = 0; ni < 4; ++ni) {
                    acc1[mi][ni] = __builtin_amdgcn_mfma_f32_16x16x32_bf16(af[mi], b1f[ni], acc1[mi][ni], 0, 0, 0);
                    acc3[mi][ni] = __builtin_amdgcn_mfma_f32_16x16x32_bf16(af[mi], b3f[ni], acc3[mi][ni], 0, 0, 0);
                }
        }
        __syncthreads();
    }

#pragma unroll
    for (int mi = 0; mi < 4; ++mi) {
        int prow_b = m0 + wm * 64 + mi * 16 + fq * 4;
#pragma unroll
        for (int r = 0; r < 4; ++r) {
            int prow = prow_b + r;
            if (prow < mEnd) {
#pragma unroll
                for (int ni = 0; ni < 4; ++ni) {
                    float h1 = acc1[mi][ni][r];
                    float h3 = acc3[mi][ni][r];
                    float vv = h1 / (1.0f + __expf(-h1)) * h3;
                    int col = n0 + wn * 64 + ni * 16 + fr;
                    pout[(size_t)prow * FDIM + col] = (bf16_t)vv;
                }
            }
        }
    }
}

// GEMM2 merged (single-writer), R9 shape: BM=128, BN=64 -> grid (16,32,8),
// 512 active blocks = 2/CU. For expert e's rows:
//   out[perm[row]] = mid_r[row] @ w2T[e]  +  mid_s[perm[row]] @ ws2T
__global__ __launch_bounds__(256, 2)
void gemm2m_bf16(const bf16_t* __restrict__ mid_r, const bf16_t* __restrict__ mid_s,
                 const bf16_t* __restrict__ w2T, const bf16_t* __restrict__ ws2T,
                 const int* __restrict__ perm, const int* __restrict__ offsets,
                 float* __restrict__ out)
{
    const int e  = blockIdx.z;
    const int n0 = blockIdx.x * 64;
    const int s  = offsets[e], eEnd = offsets[e + 1];
    const int m0 = s + blockIdx.y * 128;
    if (m0 >= eEnd) return;
    const int mEnd = eEnd;

    __shared__ __align__(16) bf16_t sA[128 * 64];
    __shared__ __align__(16) bf16_t sB[64 * 64];

    const int tid  = threadIdx.x;
    const int lane = tid & 63;
    const int wid  = tid >> 6;
    const int wm   = wid >> 1, wn = wid & 1;   // 2x2 waves: 64-row x 32-col tiles
    const int fr   = lane & 15;
    const int fq   = lane >> 4;

    f32x4 acc[4][2];
#pragma unroll
    for (int i = 0; i < 4; ++i)
#pragma unroll
        for (int j = 0; j < 2; ++j)
            acc[i][j] = (f32x4){0.f, 0.f, 0.f, 0.f};

    // per-thread gathered row pointers for the shared pass
    const int baseRow = tid >> 3;
    const bf16_t* rowPtr[4];
#pragma unroll
    for (int i = 0; i < 4; ++i) {
        int rr = m0 + baseRow + 32 * i;
        int tok = perm[rr < mEnd ? rr : m0];   // clamp: garbage rows masked at store
        rowPtr[i] = mid_s + (size_t)tok * FDIM;
    }

#define G2M_COMPUTE() do {                                                    \
        _Pragma("unroll")                                                     \
        for (int ss = 0; ss < 2; ++ss) {                                      \
            const int kg = ss * 4 + fq;                                       \
            bf16x8 af[4], bf[2];                                              \
            _Pragma("unroll")                                                 \
            for (int mi = 0; mi < 4; ++mi) {                                  \
                int r = wm * 64 + mi * 16 + fr;                               \
                af[mi] = *(const bf16x8*)((const char*)sA + swz_off(r, kg));  \
            }                                                                 \
            _Pragma("unroll")                                                 \
            for (int ni = 0; ni < 2; ++ni) {                                  \
                int r = wn * 32 + ni * 16 + fr;                               \
                bf[ni] = *(const bf16x8*)((const char*)sB + swz_off(r, kg));  \
            }                                                                 \
            _Pragma("unroll")                                                 \
            for (int mi = 0; mi < 4; ++mi)                                    \
                _Pragma("unroll")                                             \
                for (int ni = 0; ni < 2; ++ni)                                \
                    acc[mi][ni] = __builtin_amdgcn_mfma_f32_16x16x32_bf16(    \
                        af[mi], bf[ni], acc[mi][ni], 0, 0, 0);                \
        }                                                                     \
    } while (0)

    // pass 1: routed contribution  (A = mid_r rows m0.., B = w2T[e])
    {
        const bf16_t* srcA = mid_r + (size_t)m0 * FDIM;
        const bf16_t* srcB = w2T + (size_t)e * DDIM * FDIM + (size_t)n0 * FDIM;
        for (int k0 = 0; k0 < FDIM; k0 += 64) {
            stage_swz(srcA + k0, FDIM, sA, tid);
            stage_swz64(srcB + k0, FDIM, sB, tid);
            __syncthreads();
            G2M_COMPUTE();
            __syncthreads();
        }
    }
    // pass 2: shared contribution  (A = mid_s gathered rows, B = ws2T)
    {
        const bf16_t* srcB = ws2T + (size_t)n0 * FDIM;
        for (int k0 = 0; k0 < FDIM; k0 += 64) {
            stage_swz_gather(rowPtr, k0, sA, tid);
            stage_swz64(srcB + k0, FDIM, sB, tid);
            __syncthreads();
            G2M_COMPUTE();
            __syncthreads();
        }
    }
#undef G2M_COMPUTE

#pragma unroll
    for (int mi = 0; mi < 4; ++mi) {
        int prow_b = m0 + wm * 64 + mi * 16 + fq * 4;
#pragma unroll
        for (int r = 0; r < 4; ++r) {
            int prow = prow_b + r;
            if (prow < mEnd) {
                int orow = perm[prow];
#pragma unroll
                for (int ni = 0; ni < 2; ++ni) {
                    int col = n0 + wn * 32 + ni * 16 + fr;
                    out[(size_t)orow * DDIM + col] = acc[mi][ni][r];
                }
            }
        }
    }
}

// ======================= launch =======================
extern "C" void kernel_launch(void* const* d_in, const int* in_sizes, int n_in,
                              void* d_out, int out_size, void* d_ws, size_t ws_size,
                              hipStream_t stream)
{
    const float* x      = (const float*)d_in[0];
    const float* router = (const float*)d_in[1];
    const float* w1     = (const float*)d_in[2];
    const float* w3     = (const float*)d_in[3];
    const float* w2     = (const float*)d_in[4];
    const float* ws1    = (const float*)d_in[5];
    const float* ws3    = (const float*)d_in[6];
    const float* ws2    = (const float*)d_in[7];
    float* out = (float*)d_out;

    char* ws = (char*)d_ws;
    int*   idx_a   = (int*)(ws + 0);
    float* gate_a  = (float*)(ws + 16384);
    int*   offsets = (int*)(ws + 32832);
    int*   perm    = (int*)(ws + 33280);

    bf16_t* xs    = (bf16_t*)(ws + OFF_XS);
    bf16_t* xr    = (bf16_t*)(ws + OFF_XR);
    bf16_t* mid_s = (bf16_t*)(ws + OFF_MIDS);
    bf16_t* mid_r = (bf16_t*)(ws + OFF_MIDR);
    bf16_t* w1T   = (bf16_t*)(ws + OFF_W1T);
    bf16_t* w3T   = (bf16_t*)(ws + OFF_W3T);
    bf16_t* w2T   = (bf16_t*)(ws + OFF_W2T);
    bf16_t* ws1T  = (bf16_t*)(ws + OFF_WS1T);
    bf16_t* ws3T  = (bf16_t*)(ws + OFF_WS3T);
    bf16_t* ws2T  = (bf16_t*)(ws + OFF_WS2T);

    score_kernel<<<A_TOK / 4, 256, 0, stream>>>(x, router, idx_a, gate_a);
    perm_kernel<<<1, 1024, 0, stream>>>(idx_a, offsets, perm);

    prep_x_kernel<<<A_TOK, 256, 0, stream>>>(x, gate_a, perm, xs, xr);
    tconvA_kernel<<<dim3(FDIM / 64, DDIM / 64, 18), 256, 0, stream>>>(
        w1, w3, ws1, ws3, w1T, w3T, ws1T, ws3T);

    gemm1_bf16<<<dim3(FDIM / 128, 32, NEXP + 1), 256, 0, stream>>>(
        xr, xs, w1T, w3T, ws1T, ws3T, offsets, mid_r, mid_s);

    tconvB_kernel<<<dim3(DDIM / 64, FDIM / 64, 9), 256, 0, stream>>>(
        w2, ws2, w2T, ws2T);

    gemm2m_bf16<<<dim3(DDIM / 64, 32, NEXP), 256, 0, stream>>>(
        mid_r, mid_s, w2T, ws2T, perm, offsets, out);
}

// Round 10
// 336.025 us; speedup vs baseline: 1.4901x; 1.0255x over previous
//
#include <hip/hip_runtime.h>
#include <hip/hip_bf16.h>
#include <math.h>

#define A_TOK 4096
#define DDIM  1024
#define NEXP  8
#define FDIM  2816

typedef __bf16 bf16_t;
typedef __bf16 bf16x8 __attribute__((ext_vector_type(8)));
typedef __bf16 bf16x4 __attribute__((ext_vector_type(4)));
typedef __bf16 bf16x2 __attribute__((ext_vector_type(2)));
typedef float  f32x4  __attribute__((ext_vector_type(4)));

// ======================= workspace layout =======================
//   [0,16384)      int   idx_a[4096]
//   [16384,32768)  float gate_a[4096]
//   [32832,32868)  int   offsets[9]
//   [33280,49664)  int   perm[4096]
static constexpr size_t OFF_XS   = 65536;
static constexpr size_t OFF_XR   = OFF_XS   + (size_t)A_TOK * DDIM * 2;
static constexpr size_t OFF_MIDS = OFF_XR   + (size_t)(A_TOK + 128) * DDIM * 2;
static constexpr size_t OFF_MIDR = OFF_MIDS + (size_t)A_TOK * FDIM * 2;
static constexpr size_t OFF_W1T  = OFF_MIDR + (size_t)(A_TOK + 128) * FDIM * 2;
static constexpr size_t OFF_W3T  = OFF_W1T  + (size_t)NEXP * DDIM * FDIM * 2;
static constexpr size_t OFF_W2T  = OFF_W3T  + (size_t)NEXP * DDIM * FDIM * 2;
static constexpr size_t OFF_WS1T = OFF_W2T  + (size_t)NEXP * DDIM * FDIM * 2;
static constexpr size_t OFF_WS3T = OFF_WS1T + (size_t)DDIM * FDIM * 2;
static constexpr size_t OFF_WS2T = OFF_WS3T + (size_t)DDIM * FDIM * 2;
static constexpr size_t WS_NEED  = OFF_WS2T + (size_t)DDIM * FDIM * 2;   // ~209.5 MiB

// Tuning ledger (measured):
//  R3: GEMM working point: 48KB staged / 32 MFMA per barrier-pair, BK=64,
//      8-slot XOR swizzle, (256,2) -> gemm1 120.7us, MfmaUtil 34.6, 0 conflicts.
//  R4: BK=32 dbuf + __syncthreads prefetch -> conflicts + vmcnt(0) drain. REVERTED.
//  R5: XCD remap -> FETCH halved but slower (latency-bound). REVERTED.
//  R6: launch_bounds(256,3) -> VGPR squeeze, spills. REVERTED.
//  R7: tconv u32 rewrite -> neutral. Old gemm2 pair measured ~180us (not 60).
//  R8: merged single-writer gemm2, BN=128 -> 256 blocks=1/CU, 166us.
//  R9: BN=64 -> 512 blocks=2/CU, 136us, MfmaUtil 13.9. Still 16 MFMA/barrier.
//  R10: fuse routed+shared K-loops -> 48KB staged / 32 MFMA per barrier, 44
//       barrier-pairs (this round; mirrors R3's working point).

// ======================= router: scores =======================
__global__ __launch_bounds__(256)
void score_kernel(const float* __restrict__ x,
                  const float* __restrict__ router,
                  int* __restrict__ idx_a,
                  float* __restrict__ gate_a)
{
    __shared__ float rT[NEXP][DDIM];
    const int tid = threadIdx.x;
    for (int i = tid; i < DDIM * NEXP; i += 256)
        rT[i & 7][i >> 3] = router[i];
    __syncthreads();

    const int wid = tid >> 6, lane = tid & 63;
    const int t = blockIdx.x * 4 + wid;
    const float* xr = x + (size_t)t * DDIM;

    double s[NEXP];
#pragma unroll
    for (int e = 0; e < NEXP; ++e) s[e] = 0.0;
#pragma unroll
    for (int i = 0; i < DDIM / 64; ++i) {
        int d = i * 64 + lane;
        float xv = xr[d];
#pragma unroll
        for (int e = 0; e < NEXP; ++e)
            s[e] += (double)xv * (double)rT[e][d];
    }
#pragma unroll
    for (int e = 0; e < NEXP; ++e) {
#pragma unroll
        for (int off = 32; off > 0; off >>= 1)
            s[e] += __shfl_xor(s[e], off);
    }
    if (lane == 0) {
        int best = 0; double bv = s[0];
#pragma unroll
        for (int e = 1; e < NEXP; ++e)
            if (s[e] > bv) { bv = s[e]; best = e; }
        idx_a[t] = best;
        gate_a[t] = 1.0f / (1.0f + expf(-(float)bv));
    }
}

// ======================= fused count + scan + scatter =======================
__global__ __launch_bounds__(1024)
void perm_kernel(const int* __restrict__ idx_a,
                 int* __restrict__ offsets,
                 int* __restrict__ perm)
{
    __shared__ int cnt[NEXP];
    __shared__ int base[NEXP];
    const int tid = threadIdx.x;
    if (tid < NEXP) cnt[tid] = 0;
    __syncthreads();

    int e[4];
#pragma unroll
    for (int j = 0; j < 4; ++j) {
        e[j] = idx_a[j * 1024 + tid];
        atomicAdd(&cnt[e[j]], 1);
    }
    __syncthreads();
    if (tid == 0) {
        int acc = 0;
#pragma unroll
        for (int k = 0; k < NEXP; ++k) {
            base[k] = acc; offsets[k] = acc; acc += cnt[k];
        }
        offsets[NEXP] = acc;
    }
    __syncthreads();
#pragma unroll
    for (int j = 0; j < 4; ++j) {
        int t = j * 1024 + tid;
        int pos = atomicAdd(&base[e[j]], 1);
        perm[pos] = t;
    }
}

// ======================= prep kernels =======================
__global__ void prep_x_kernel(const float* __restrict__ x,
                              const float* __restrict__ gate_a,
                              const int* __restrict__ perm,
                              bf16_t* __restrict__ xs,
                              bf16_t* __restrict__ xr)
{
    const int p = blockIdx.x;
    const int d = threadIdx.x * 4;
    float4 v = *(const float4*)(x + (size_t)p * DDIM + d);
    bf16x4 o;
    o[0] = (bf16_t)v.x; o[1] = (bf16_t)v.y; o[2] = (bf16_t)v.z; o[3] = (bf16_t)v.w;
    *(bf16x4*)(xs + (size_t)p * DDIM + d) = o;

    const int tok = perm[p];
    const float g = gate_a[tok];
    float4 w = *(const float4*)(x + (size_t)tok * DDIM + d);
    bf16x4 o2;
    o2[0] = (bf16_t)(w.x * g); o2[1] = (bf16_t)(w.y * g);
    o2[2] = (bf16_t)(w.z * g); o2[3] = (bf16_t)(w.w * g);
    *(bf16x4*)(xr + (size_t)p * DDIM + d) = o2;
}

// pack two fp32 rows' element into one u32 of 2 bf16 (low = first row)
__device__ __forceinline__ unsigned pk2(float a, float b)
{
    union { bf16x2 v; unsigned u; } x;
    x.v[0] = (bf16_t)a; x.v[1] = (bf16_t)b;
    return x.u;
}

// transpose+convert core: src [R][C] fp32 -> dst [C][R] bf16, one 64x64 tile.
__device__ __forceinline__ void tconv_tile(const float* __restrict__ src,
                                           bf16_t* __restrict__ dst,
                                           int R, int C, int r0, int c0)
{
    __shared__ unsigned t2[64][33];
    const int tid = threadIdx.x;
    const int cl = (tid & 15) * 4;
    const int rh = tid >> 4;
#pragma unroll
    for (int i = 0; i < 2; ++i) {
        const int r = rh * 2 + i * 32;
        const float* s0 = src + (size_t)(r0 + r) * C + c0 + cl;
        float4 v0 = *(const float4*)s0;
        float4 v1 = *(const float4*)(s0 + C);
        t2[cl + 0][rh + i * 16] = pk2(v0.x, v1.x);
        t2[cl + 1][rh + i * 16] = pk2(v0.y, v1.y);
        t2[cl + 2][rh + i * 16] = pk2(v0.z, v1.z);
        t2[cl + 3][rh + i * 16] = pk2(v0.w, v1.w);
    }
    __syncthreads();
    const int c2 = tid >> 3;
    const int rq = (tid & 7) * 4;
#pragma unroll
    for (int i = 0; i < 2; ++i) {
        const int c = c2 + i * 32;
        uint4 vv;
        vv.x = t2[c][rq + 0];
        vv.y = t2[c][rq + 1];
        vv.z = t2[c][rq + 2];
        vv.w = t2[c][rq + 3];
        *(uint4*)(dst + (size_t)(c0 + c) * R + r0 + rq * 2) = vv;
    }
}

__global__ void tconvA_kernel(const float* __restrict__ w1, const float* __restrict__ w3,
                              const float* __restrict__ ws1, const float* __restrict__ ws3,
                              bf16_t* __restrict__ w1T, bf16_t* __restrict__ w3T,
                              bf16_t* __restrict__ ws1T, bf16_t* __restrict__ ws3T)
{
    const int z = blockIdx.z;
    const size_t ms = (size_t)DDIM * FDIM;
    const float* src; bf16_t* dst;
    if (z < 8)       { src = w1 + (size_t)z * ms;       dst = w1T + (size_t)z * ms; }
    else if (z < 16) { src = w3 + (size_t)(z - 8) * ms; dst = w3T + (size_t)(z - 8) * ms; }
    else if (z == 16){ src = ws1;                        dst = ws1T; }
    else             { src = ws3;                        dst = ws3T; }
    tconv_tile(src, dst, DDIM, FDIM, blockIdx.y * 64, blockIdx.x * 64);
}

__global__ void tconvB_kernel(const float* __restrict__ w2, const float* __restrict__ ws2,
                              bf16_t* __restrict__ w2T, bf16_t* __restrict__ ws2T)
{
    const int z = blockIdx.z;
    const size_t ms = (size_t)DDIM * FDIM;
    const float* src; bf16_t* dst;
    if (z < 8) { src = w2 + (size_t)z * ms; dst = w2T + (size_t)z * ms; }
    else       { src = ws2;                  dst = ws2T; }
    tconv_tile(src, dst, FDIM, DDIM, blockIdx.y * 64, blockIdx.x * 64);
}

// ======================= bf16 GEMM machinery =======================
__device__ __forceinline__ void glds16(const bf16_t* g, bf16_t* l)
{
    __builtin_amdgcn_global_load_lds(
        (const __attribute__((address_space(1))) void*)g,
        (__attribute__((address_space(3))) void*)l, 16, 0, 0);
}

// stage 128 rows x 64 bf16 (128B/row), XOR-swizzled on 16B slots (8 slots/row):
// LDS[row][slot] = global[row][slot ^ (row&7)]   -- measured 0 bank conflicts
__device__ __forceinline__ void stage_swz(const bf16_t* __restrict__ src,
                                          size_t stride, bf16_t* lds, int tid)
{
#pragma unroll
    for (int i = 0; i < 4; ++i) {
        int o = i * 256 + tid;
        int row = o >> 3;
        int slot = o & 7;
        int srcSlot = slot ^ (row & 7);
        glds16(src + (size_t)row * stride + srcSlot * 8, lds + (size_t)o * 8);
    }
}

// 64-row variant (B tiles for gemm2m)
__device__ __forceinline__ void stage_swz64(const bf16_t* __restrict__ src,
                                            size_t stride, bf16_t* lds, int tid)
{
#pragma unroll
    for (int i = 0; i < 2; ++i) {
        int o = i * 256 + tid;          // 0..511
        int row = o >> 3;               // 0..63
        int slot = o & 7;
        int srcSlot = slot ^ (row & 7);
        glds16(src + (size_t)row * stride + srcSlot * 8, lds + (size_t)o * 8);
    }
}

// gathered variant: per-thread row base pointers (4 rows/thread), same swizzle.
__device__ __forceinline__ void stage_swz_gather(const bf16_t* const* rowPtr,
                                                 int k0, bf16_t* lds, int tid)
{
#pragma unroll
    for (int i = 0; i < 4; ++i) {
        int o = i * 256 + tid;
        int row = o >> 3;
        int slot = o & 7;
        int srcSlot = slot ^ (row & 7);
        glds16(rowPtr[i] + k0 + srcSlot * 8, lds + (size_t)o * 8);
    }
}

__device__ __forceinline__ int swz_off(int row, int g16)
{
    return row * 128 + ((g16 ^ (row & 7)) << 4);
}

// GEMM1: mid = silu(A@W1T^T) * (A@W3T^T); 128x128 tile, BK=64, single buffer
__global__ __launch_bounds__(256, 2)
void gemm1_bf16(const bf16_t* __restrict__ xr, const bf16_t* __restrict__ xs,
                const bf16_t* __restrict__ w1T, const bf16_t* __restrict__ w3T,
                const bf16_t* __restrict__ ws1T, const bf16_t* __restrict__ ws3T,
                const int* __restrict__ offsets,
                bf16_t* __restrict__ mid_r, bf16_t* __restrict__ mid_s)
{
    const int g  = blockIdx.z;
    const int n0 = blockIdx.x * 128;
    int m0, mEnd;
    const bf16_t *pa, *pw1, *pw3;
    bf16_t* pout;
    if (g < NEXP) {
        int s = offsets[g], e = offsets[g + 1];
        m0 = s + blockIdx.y * 128;
        if (m0 >= e) return;
        mEnd = e;
        pa = xr;
        pw1 = w1T + (size_t)g * DDIM * FDIM;
        pw3 = w3T + (size_t)g * DDIM * FDIM;
        pout = mid_r;
    } else {
        m0 = blockIdx.y * 128;
        mEnd = A_TOK;
        pa = xs; pw1 = ws1T; pw3 = ws3T; pout = mid_s;
    }

    __shared__ __align__(16) bf16_t sA[128 * 64];
    __shared__ __align__(16) bf16_t sB1[128 * 64];
    __shared__ __align__(16) bf16_t sB3[128 * 64];

    const int tid  = threadIdx.x;
    const int lane = tid & 63;
    const int wid  = tid >> 6;
    const int wm   = wid >> 1, wn = wid & 1;
    const int fr   = lane & 15;
    const int fq   = lane >> 4;

    f32x4 acc1[4][4], acc3[4][4];
#pragma unroll
    for (int i = 0; i < 4; ++i)
#pragma unroll
        for (int j = 0; j < 4; ++j) {
            acc1[i][j] = (f32x4){0.f, 0.f, 0.f, 0.f};
            acc3[i][j] = (f32x4){0.f, 0.f, 0.f, 0.f};
        }

    const bf16_t* srcA  = pa  + (size_t)m0 * DDIM;
    const bf16_t* srcB1 = pw1 + (size_t)n0 * DDIM;
    const bf16_t* srcB3 = pw3 + (size_t)n0 * DDIM;

    for (int k0 = 0; k0 < DDIM; k0 += 64) {
        stage_swz(srcA  + k0, DDIM, sA,  tid);
        stage_swz(srcB1 + k0, DDIM, sB1, tid);
        stage_swz(srcB3 + k0, DDIM, sB3, tid);
        __syncthreads();

#pragma unroll
        for (int s = 0; s < 2; ++s) {
            const int kg = s * 4 + fq;
            bf16x8 af[4], b1f[4], b3f[4];
#pragma unroll
            for (int mi = 0; mi < 4; ++mi) {
                int r = wm * 64 + mi * 16 + fr;
                af[mi] = *(const bf16x8*)((const char*)sA + swz_off(r, kg));
            }
#pragma unroll
            for (int ni = 0; ni < 4; ++ni) {
                int r = wn * 64 + ni * 16 + fr;
                b1f[ni] = *(const bf16x8*)((const char*)sB1 + swz_off(r, kg));
                b3f[ni] = *(const bf16x8*)((const char*)sB3 + swz_off(r, kg));
            }
#pragma unroll
            for (int mi = 0; mi < 4; ++mi)
#pragma unroll
                for (int ni = 0; ni < 4; ++ni) {
                    acc1[mi][ni] = __builtin_amdgcn_mfma_f32_16x16x32_bf16(af[mi], b1f[ni], acc1[mi][ni], 0, 0, 0);
                    acc3[mi][ni] = __builtin_amdgcn_mfma_f32_16x16x32_bf16(af[mi], b3f[ni], acc3[mi][ni], 0, 0, 0);
                }
        }
        __syncthreads();
    }

#pragma unroll
    for (int mi = 0; mi < 4; ++mi) {
        int prow_b = m0 + wm * 64 + mi * 16 + fq * 4;
#pragma unroll
        for (int r = 0; r < 4; ++r) {
            int prow = prow_b + r;
            if (prow < mEnd) {
#pragma unroll
                for (int ni = 0; ni < 4; ++ni) {
                    float h1 = acc1[mi][ni][r];
                    float h3 = acc3[mi][ni][r];
                    float vv = h1 / (1.0f + __expf(-h1)) * h3;
                    int col = n0 + wn * 64 + ni * 16 + fr;
                    pout[(size_t)prow * FDIM + col] = (bf16_t)vv;
                }
            }
        }
    }
}

// GEMM2 merged + fused-K (single-writer), R10:
//   out[perm[row]] = mid_r[row] @ w2T[e]  +  mid_s[perm[row]] @ ws2T
// ONE K-loop: per K-step stage {Ar 16KB, As 16KB, Br 8KB, Bs 8KB} and fire
// 32 MFMA into one accumulator -> R3's proven 48KB/32-MFMA working point.
__global__ __launch_bounds__(256, 2)
void gemm2m_bf16(const bf16_t* __restrict__ mid_r, const bf16_t* __restrict__ mid_s,
                 const bf16_t* __restrict__ w2T, const bf16_t* __restrict__ ws2T,
                 const int* __restrict__ perm, const int* __restrict__ offsets,
                 float* __restrict__ out)
{
    const int e  = blockIdx.z;
    const int n0 = blockIdx.x * 64;
    const int s  = offsets[e], eEnd = offsets[e + 1];
    const int m0 = s + blockIdx.y * 128;
    if (m0 >= eEnd) return;
    const int mEnd = eEnd;

    __shared__ __align__(16) bf16_t sAr[128 * 64];
    __shared__ __align__(16) bf16_t sAs[128 * 64];
    __shared__ __align__(16) bf16_t sBr[64 * 64];
    __shared__ __align__(16) bf16_t sBs[64 * 64];

    const int tid  = threadIdx.x;
    const int lane = tid & 63;
    const int wid  = tid >> 6;
    const int wm   = wid >> 1, wn = wid & 1;   // 2x2 waves: 64-row x 32-col tiles
    const int fr   = lane & 15;
    const int fq   = lane >> 4;

    f32x4 acc[4][2];
#pragma unroll
    for (int i = 0; i < 4; ++i)
#pragma unroll
        for (int j = 0; j < 2; ++j)
            acc[i][j] = (f32x4){0.f, 0.f, 0.f, 0.f};

    // per-thread gathered row pointers for the shared contribution
    const int baseRow = tid >> 3;
    const bf16_t* rowPtr[4];
#pragma unroll
    for (int i = 0; i < 4; ++i) {
        int rr = m0 + baseRow + 32 * i;
        int tok = perm[rr < mEnd ? rr : m0];   // clamp: garbage rows masked at store
        rowPtr[i] = mid_s + (size_t)tok * FDIM;
    }

    const bf16_t* srcAr = mid_r + (size_t)m0 * FDIM;
    const bf16_t* srcBr = w2T + (size_t)e * DDIM * FDIM + (size_t)n0 * FDIM;
    const bf16_t* srcBs = ws2T + (size_t)n0 * FDIM;

    for (int k0 = 0; k0 < FDIM; k0 += 64) {
        stage_swz(srcAr + k0, FDIM, sAr, tid);
        stage_swz_gather(rowPtr, k0, sAs, tid);
        stage_swz64(srcBr + k0, FDIM, sBr, tid);
        stage_swz64(srcBs + k0, FDIM, sBs, tid);
        __syncthreads();

#pragma unroll
        for (int ss = 0; ss < 2; ++ss) {
            const int kg = ss * 4 + fq;
            bf16x8 ar[4], br[2], as[4], bs[2];
#pragma unroll
            for (int mi = 0; mi < 4; ++mi) {
                int r = wm * 64 + mi * 16 + fr;
                ar[mi] = *(const bf16x8*)((const char*)sAr + swz_off(r, kg));
                as[mi] = *(const bf16x8*)((const char*)sAs + swz_off(r, kg));
            }
#pragma unroll
            for (int ni = 0; ni < 2; ++ni) {
                int r = wn * 32 + ni * 16 + fr;
                br[ni] = *(const bf16x8*)((const char*)sBr + swz_off(r, kg));
                bs[ni] = *(const bf16x8*)((const char*)sBs + swz_off(r, kg));
            }
#pragma unroll
            for (int mi = 0; mi < 4; ++mi)
#pragma unroll
                for (int ni = 0; ni < 2; ++ni) {
                    acc[mi][ni] = __builtin_amdgcn_mfma_f32_16x16x32_bf16(ar[mi], br[ni], acc[mi][ni], 0, 0, 0);
                    acc[mi][ni] = __builtin_amdgcn_mfma_f32_16x16x32_bf16(as[mi], bs[ni], acc[mi][ni], 0, 0, 0);
                }
        }
        __syncthreads();
    }

#pragma unroll
    for (int mi = 0; mi < 4; ++mi) {
        int prow_b = m0 + wm * 64 + mi * 16 + fq * 4;
#pragma unroll
        for (int r = 0; r < 4; ++r) {
            int prow = prow_b + r;
            if (prow < mEnd) {
                int orow = perm[prow];
#pragma unroll
                for (int ni = 0; ni < 2; ++ni) {
                    int col = n0 + wn * 32 + ni * 16 + fr;
                    out[(size_t)orow * DDIM + col] = acc[mi][ni][r];
                }
            }
        }
    }
}

// ======================= launch =======================
extern "C" void kernel_launch(void* const* d_in, const int* in_sizes, int n_in,
                              void* d_out, int out_size, void* d_ws, size_t ws_size,
                              hipStream_t stream)
{
    const float* x      = (const float*)d_in[0];
    const float* router = (const float*)d_in[1];
    const float* w1     = (const float*)d_in[2];
    const float* w3     = (const float*)d_in[3];
    const float* w2     = (const float*)d_in[4];
    const float* ws1    = (const float*)d_in[5];
    const float* ws3    = (const float*)d_in[6];
    const float* ws2    = (const float*)d_in[7];
    float* out = (float*)d_out;

    char* ws = (char*)d_ws;
    int*   idx_a   = (int*)(ws + 0);
    float* gate_a  = (float*)(ws + 16384);
    int*   offsets = (int*)(ws + 32832);
    int*   perm    = (int*)(ws + 33280);

    bf16_t* xs    = (bf16_t*)(ws + OFF_XS);
    bf16_t* xr    = (bf16_t*)(ws + OFF_XR);
    bf16_t* mid_s = (bf16_t*)(ws + OFF_MIDS);
    bf16_t* mid_r = (bf16_t*)(ws + OFF_MIDR);
    bf16_t* w1T   = (bf16_t*)(ws + OFF_W1T);
    bf16_t* w3T   = (bf16_t*)(ws + OFF_W3T);
    bf16_t* w2T   = (bf16_t*)(ws + OFF_W2T);
    bf16_t* ws1T  = (bf16_t*)(ws + OFF_WS1T);
    bf16_t* ws3T  = (bf16_t*)(ws + OFF_WS3T);
    bf16_t* ws2T  = (bf16_t*)(ws + OFF_WS2T);

    score_kernel<<<A_TOK / 4, 256, 0, stream>>>(x, router, idx_a, gate_a);
    perm_kernel<<<1, 1024, 0, stream>>>(idx_a, offsets, perm);

    prep_x_kernel<<<A_TOK, 256, 0, stream>>>(x, gate_a, perm, xs, xr);
    tconvA_kernel<<<dim3(FDIM / 64, DDIM / 64, 18), 256, 0, stream>>>(
        w1, w3, ws1, ws3, w1T, w3T, ws1T, ws3T);

    gemm1_bf16<<<dim3(FDIM / 128, 32, NEXP + 1), 256, 0, stream>>>(
        xr, xs, w1T, w3T, ws1T, ws3T, offsets, mid_r, mid_s);

    tconvB_kernel<<<dim3(DDIM / 64, FDIM / 64, 9), 256, 0, stream>>>(
        w2, ws2, w2T, ws2T);

    gemm2m_bf16<<<dim3(DDIM / 64, 32, NEXP), 256, 0, stream>>>(
        mid_r, mid_s, w2T, ws2T, perm, offsets, out);
}

// Round 11
// 322.702 us; speedup vs baseline: 1.5516x; 1.0413x over previous
//
#include <hip/hip_runtime.h>
#include <hip/hip_bf16.h>
#include <math.h>

#define A_TOK 4096
#define DDIM  1024
#define NEXP  8
#define FDIM  2816
#define KHALF 1408

typedef __bf16 bf16_t;
typedef __bf16 bf16x8 __attribute__((ext_vector_type(8)));
typedef __bf16 bf16x4 __attribute__((ext_vector_type(4)));
typedef __bf16 bf16x2 __attribute__((ext_vector_type(2)));
typedef float  f32x4  __attribute__((ext_vector_type(4)));

// ======================= workspace layout =======================
//   [0,16384)      int   idx_a[4096]
//   [16384,32768)  float gate_a[4096]
//   [32832,32868)  int   offsets[9]
//   [33280,49664)  int   perm[4096]
static constexpr size_t OFF_XS   = 65536;
static constexpr size_t OFF_XR   = OFF_XS   + (size_t)A_TOK * DDIM * 2;
static constexpr size_t OFF_MIDS = OFF_XR   + (size_t)(A_TOK + 128) * DDIM * 2;
static constexpr size_t OFF_MIDR = OFF_MIDS + (size_t)A_TOK * FDIM * 2;
static constexpr size_t OFF_W1T  = OFF_MIDR + (size_t)(A_TOK + 128) * FDIM * 2;
static constexpr size_t OFF_W3T  = OFF_W1T  + (size_t)NEXP * DDIM * FDIM * 2;
static constexpr size_t OFF_W2T  = OFF_W3T  + (size_t)NEXP * DDIM * FDIM * 2;
static constexpr size_t OFF_WS1T = OFF_W2T  + (size_t)NEXP * DDIM * FDIM * 2;
static constexpr size_t OFF_WS3T = OFF_WS1T + (size_t)DDIM * FDIM * 2;
static constexpr size_t OFF_WS2T = OFF_WS3T + (size_t)DDIM * FDIM * 2;
static constexpr size_t WS_NEED  = OFF_WS2T + (size_t)DDIM * FDIM * 2;   // ~209.5 MiB
// outP (split-K partial, 16.8MB fp32) aliases the dead w1T region: w1T is only
// read by gemm1, which completes before gemm2m runs.
static constexpr size_t OFF_OUTP = OFF_W1T;

// Tuning ledger (measured):
//  R3: GEMM working point: BK=64, 8-slot XOR swizzle, (256,2) -> gemm1 120.7us,
//      MfmaUtil 34.6 (64 MFMA/wave/barrier), 0 conflicts.
//  R4: BK=32 dbuf + __syncthreads prefetch -> conflicts + vmcnt(0) drain. REVERTED.
//  R5: XCD remap -> FETCH halved but slower (latency-bound). REVERTED.
//  R6: launch_bounds(256,3) -> VGPR squeeze, spills. REVERTED. Keep (256,2).
//  R7: tconv u32 rewrite -> neutral (BW-floor).
//  R8: merged single-writer gemm2, BN=128 -> 256 blocks=1/CU, 166us.
//  R9: BN=64 -> 512 blocks=2/CU, 136us (16 MFMA/wave/barrier).
//  R10: fused routed+shared K-loop -> 123us, MfmaUtil 15.4. Still only
//       32 MFMA/wave/barrier (half of gemm1) and 44-step serial chain.
//  R11: split-K=2 + outP add pass -> 22-step chain, 1024 active blocks (this).

// ======================= router: scores =======================
__global__ __launch_bounds__(256)
void score_kernel(const float* __restrict__ x,
                  const float* __restrict__ router,
                  int* __restrict__ idx_a,
                  float* __restrict__ gate_a)
{
    __shared__ float rT[NEXP][DDIM];
    const int tid = threadIdx.x;
    for (int i = tid; i < DDIM * NEXP; i += 256)
        rT[i & 7][i >> 3] = router[i];
    __syncthreads();

    const int wid = tid >> 6, lane = tid & 63;
    const int t = blockIdx.x * 4 + wid;
    const float* xr = x + (size_t)t * DDIM;

    double s[NEXP];
#pragma unroll
    for (int e = 0; e < NEXP; ++e) s[e] = 0.0;
#pragma unroll
    for (int i = 0; i < DDIM / 64; ++i) {
        int d = i * 64 + lane;
        float xv = xr[d];
#pragma unroll
        for (int e = 0; e < NEXP; ++e)
            s[e] += (double)xv * (double)rT[e][d];
    }
#pragma unroll
    for (int e = 0; e < NEXP; ++e) {
#pragma unroll
        for (int off = 32; off > 0; off >>= 1)
            s[e] += __shfl_xor(s[e], off);
    }
    if (lane == 0) {
        int best = 0; double bv = s[0];
#pragma unroll
        for (int e = 1; e < NEXP; ++e)
            if (s[e] > bv) { bv = s[e]; best = e; }
        idx_a[t] = best;
        gate_a[t] = 1.0f / (1.0f + expf(-(float)bv));
    }
}

// ======================= fused count + scan + scatter =======================
__global__ __launch_bounds__(1024)
void perm_kernel(const int* __restrict__ idx_a,
                 int* __restrict__ offsets,
                 int* __restrict__ perm)
{
    __shared__ int cnt[NEXP];
    __shared__ int base[NEXP];
    const int tid = threadIdx.x;
    if (tid < NEXP) cnt[tid] = 0;
    __syncthreads();

    int e[4];
#pragma unroll
    for (int j = 0; j < 4; ++j) {
        e[j] = idx_a[j * 1024 + tid];
        atomicAdd(&cnt[e[j]], 1);
    }
    __syncthreads();
    if (tid == 0) {
        int acc = 0;
#pragma unroll
        for (int k = 0; k < NEXP; ++k) {
            base[k] = acc; offsets[k] = acc; acc += cnt[k];
        }
        offsets[NEXP] = acc;
    }
    __syncthreads();
#pragma unroll
    for (int j = 0; j < 4; ++j) {
        int t = j * 1024 + tid;
        int pos = atomicAdd(&base[e[j]], 1);
        perm[pos] = t;
    }
}

// ======================= prep kernels =======================
__global__ void prep_x_kernel(const float* __restrict__ x,
                              const float* __restrict__ gate_a,
                              const int* __restrict__ perm,
                              bf16_t* __restrict__ xs,
                              bf16_t* __restrict__ xr)
{
    const int p = blockIdx.x;
    const int d = threadIdx.x * 4;
    float4 v = *(const float4*)(x + (size_t)p * DDIM + d);
    bf16x4 o;
    o[0] = (bf16_t)v.x; o[1] = (bf16_t)v.y; o[2] = (bf16_t)v.z; o[3] = (bf16_t)v.w;
    *(bf16x4*)(xs + (size_t)p * DDIM + d) = o;

    const int tok = perm[p];
    const float g = gate_a[tok];
    float4 w = *(const float4*)(x + (size_t)tok * DDIM + d);
    bf16x4 o2;
    o2[0] = (bf16_t)(w.x * g); o2[1] = (bf16_t)(w.y * g);
    o2[2] = (bf16_t)(w.z * g); o2[3] = (bf16_t)(w.w * g);
    *(bf16x4*)(xr + (size_t)p * DDIM + d) = o2;
}

// pack two fp32 rows' element into one u32 of 2 bf16 (low = first row)
__device__ __forceinline__ unsigned pk2(float a, float b)
{
    union { bf16x2 v; unsigned u; } x;
    x.v[0] = (bf16_t)a; x.v[1] = (bf16_t)b;
    return x.u;
}

// transpose+convert core: src [R][C] fp32 -> dst [C][R] bf16, one 64x64 tile.
__device__ __forceinline__ void tconv_tile(const float* __restrict__ src,
                                           bf16_t* __restrict__ dst,
                                           int R, int C, int r0, int c0)
{
    __shared__ unsigned t2[64][33];
    const int tid = threadIdx.x;
    const int cl = (tid & 15) * 4;
    const int rh = tid >> 4;
#pragma unroll
    for (int i = 0; i < 2; ++i) {
        const int r = rh * 2 + i * 32;
        const float* s0 = src + (size_t)(r0 + r) * C + c0 + cl;
        float4 v0 = *(const float4*)s0;
        float4 v1 = *(const float4*)(s0 + C);
        t2[cl + 0][rh + i * 16] = pk2(v0.x, v1.x);
        t2[cl + 1][rh + i * 16] = pk2(v0.y, v1.y);
        t2[cl + 2][rh + i * 16] = pk2(v0.z, v1.z);
        t2[cl + 3][rh + i * 16] = pk2(v0.w, v1.w);
    }
    __syncthreads();
    const int c2 = tid >> 3;
    const int rq = (tid & 7) * 4;
#pragma unroll
    for (int i = 0; i < 2; ++i) {
        const int c = c2 + i * 32;
        uint4 vv;
        vv.x = t2[c][rq + 0];
        vv.y = t2[c][rq + 1];
        vv.z = t2[c][rq + 2];
        vv.w = t2[c][rq + 3];
        *(uint4*)(dst + (size_t)(c0 + c) * R + r0 + rq * 2) = vv;
    }
}

__global__ void tconvA_kernel(const float* __restrict__ w1, const float* __restrict__ w3,
                              const float* __restrict__ ws1, const float* __restrict__ ws3,
                              bf16_t* __restrict__ w1T, bf16_t* __restrict__ w3T,
                              bf16_t* __restrict__ ws1T, bf16_t* __restrict__ ws3T)
{
    const int z = blockIdx.z;
    const size_t ms = (size_t)DDIM * FDIM;
    const float* src; bf16_t* dst;
    if (z < 8)       { src = w1 + (size_t)z * ms;       dst = w1T + (size_t)z * ms; }
    else if (z < 16) { src = w3 + (size_t)(z - 8) * ms; dst = w3T + (size_t)(z - 8) * ms; }
    else if (z == 16){ src = ws1;                        dst = ws1T; }
    else             { src = ws3;                        dst = ws3T; }
    tconv_tile(src, dst, DDIM, FDIM, blockIdx.y * 64, blockIdx.x * 64);
}

__global__ void tconvB_kernel(const float* __restrict__ w2, const float* __restrict__ ws2,
                              bf16_t* __restrict__ w2T, bf16_t* __restrict__ ws2T)
{
    const int z = blockIdx.z;
    const size_t ms = (size_t)DDIM * FDIM;
    const float* src; bf16_t* dst;
    if (z < 8) { src = w2 + (size_t)z * ms; dst = w2T + (size_t)z * ms; }
    else       { src = ws2;                  dst = ws2T; }
    tconv_tile(src, dst, FDIM, DDIM, blockIdx.y * 64, blockIdx.x * 64);
}

// ======================= bf16 GEMM machinery =======================
__device__ __forceinline__ void glds16(const bf16_t* g, bf16_t* l)
{
    __builtin_amdgcn_global_load_lds(
        (const __attribute__((address_space(1))) void*)g,
        (__attribute__((address_space(3))) void*)l, 16, 0, 0);
}

// stage 128 rows x 64 bf16 (128B/row), XOR-swizzled on 16B slots (8 slots/row):
// LDS[row][slot] = global[row][slot ^ (row&7)]   -- measured 0 bank conflicts
__device__ __forceinline__ void stage_swz(const bf16_t* __restrict__ src,
                                          size_t stride, bf16_t* lds, int tid)
{
#pragma unroll
    for (int i = 0; i < 4; ++i) {
        int o = i * 256 + tid;
        int row = o >> 3;
        int slot = o & 7;
        int srcSlot = slot ^ (row & 7);
        glds16(src + (size_t)row * stride + srcSlot * 8, lds + (size_t)o * 8);
    }
}

// 64-row variant (B tiles for gemm2m)
__device__ __forceinline__ void stage_swz64(const bf16_t* __restrict__ src,
                                            size_t stride, bf16_t* lds, int tid)
{
#pragma unroll
    for (int i = 0; i < 2; ++i) {
        int o = i * 256 + tid;          // 0..511
        int row = o >> 3;               // 0..63
        int slot = o & 7;
        int srcSlot = slot ^ (row & 7);
        glds16(src + (size_t)row * stride + srcSlot * 8, lds + (size_t)o * 8);
    }
}

// gathered variant: per-thread row base pointers (4 rows/thread), same swizzle.
__device__ __forceinline__ void stage_swz_gather(const bf16_t* const* rowPtr,
                                                 int k0, bf16_t* lds, int tid)
{
#pragma unroll
    for (int i = 0; i < 4; ++i) {
        int o = i * 256 + tid;
        int row = o >> 3;
        int slot = o & 7;
        int srcSlot = slot ^ (row & 7);
        glds16(rowPtr[i] + k0 + srcSlot * 8, lds + (size_t)o * 8);
    }
}

__device__ __forceinline__ int swz_off(int row, int g16)
{
    return row * 128 + ((g16 ^ (row & 7)) << 4);
}

// GEMM1: mid = silu(A@W1T^T) * (A@W3T^T); 128x128 tile, BK=64, single buffer
__global__ __launch_bounds__(256, 2)
void gemm1_bf16(const bf16_t* __restrict__ xr, const bf16_t* __restrict__ xs,
                const bf16_t* __restrict__ w1T, const bf16_t* __restrict__ w3T,
                const bf16_t* __restrict__ ws1T, const bf16_t* __restrict__ ws3T,
                const int* __restrict__ offsets,
                bf16_t* __restrict__ mid_r, bf16_t* __restrict__ mid_s)
{
    const int g  = blockIdx.z;
    const int n0 = blockIdx.x * 128;
    int m0, mEnd;
    const bf16_t *pa, *pw1, *pw3;
    bf16_t* pout;
    if (g < NEXP) {
        int s = offsets[g], e = offsets[g + 1];
        m0 = s + blockIdx.y * 128;
        if (m0 >= e) return;
        mEnd = e;
        pa = xr;
        pw1 = w1T + (size_t)g * DDIM * FDIM;
        pw3 = w3T + (size_t)g * DDIM * FDIM;
        pout = mid_r;
    } else {
        m0 = blockIdx.y * 128;
        mEnd = A_TOK;
        pa = xs; pw1 = ws1T; pw3 = ws3T; pout = mid_s;
    }

    __shared__ __align__(16) bf16_t sA[128 * 64];
    __shared__ __align__(16) bf16_t sB1[128 * 64];
    __shared__ __align__(16) bf16_t sB3[128 * 64];

    const int tid  = threadIdx.x;
    const int lane = tid & 63;
    const int wid  = tid >> 6;
    const int wm   = wid >> 1, wn = wid & 1;
    const int fr   = lane & 15;
    const int fq   = lane >> 4;

    f32x4 acc1[4][4], acc3[4][4];
#pragma unroll
    for (int i = 0; i < 4; ++i)
#pragma unroll
        for (int j = 0; j < 4; ++j) {
            acc1[i][j] = (f32x4){0.f, 0.f, 0.f, 0.f};
            acc3[i][j] = (f32x4){0.f, 0.f, 0.f, 0.f};
        }

    const bf16_t* srcA  = pa  + (size_t)m0 * DDIM;
    const bf16_t* srcB1 = pw1 + (size_t)n0 * DDIM;
    const bf16_t* srcB3 = pw3 + (size_t)n0 * DDIM;

    for (int k0 = 0; k0 < DDIM; k0 += 64) {
        stage_swz(srcA  + k0, DDIM, sA,  tid);
        stage_swz(srcB1 + k0, DDIM, sB1, tid);
        stage_swz(srcB3 + k0, DDIM, sB3, tid);
        __syncthreads();

#pragma unroll
        for (int s = 0; s < 2; ++s) {
            const int kg = s * 4 + fq;
            bf16x8 af[4], b1f[4], b3f[4];
#pragma unroll
            for (int mi = 0; mi < 4; ++mi) {
                int r = wm * 64 + mi * 16 + fr;
                af[mi] = *(const bf16x8*)((const char*)sA + swz_off(r, kg));
            }
#pragma unroll
            for (int ni = 0; ni < 4; ++ni) {
                int r = wn * 64 + ni * 16 + fr;
                b1f[ni] = *(const bf16x8*)((const char*)sB1 + swz_off(r, kg));
                b3f[ni] = *(const bf16x8*)((const char*)sB3 + swz_off(r, kg));
            }
#pragma unroll
            for (int mi = 0; mi < 4; ++mi)
#pragma unroll
                for (int ni = 0; ni < 4; ++ni) {
                    acc1[mi][ni] = __builtin_amdgcn_mfma_f32_16x16x32_bf16(af[mi], b1f[ni], acc1[mi][ni], 0, 0, 0);
                    acc3[mi][ni] = __builtin_amdgcn_mfma_f32_16x16x32_bf16(af[mi], b3f[ni], acc3[mi][ni], 0, 0, 0);
                }
        }
        __syncthreads();
    }

#pragma unroll
    for (int mi = 0; mi < 4; ++mi) {
        int prow_b = m0 + wm * 64 + mi * 16 + fq * 4;
#pragma unroll
        for (int r = 0; r < 4; ++r) {
            int prow = prow_b + r;
            if (prow < mEnd) {
#pragma unroll
                for (int ni = 0; ni < 4; ++ni) {
                    float h1 = acc1[mi][ni][r];
                    float h3 = acc3[mi][ni][r];
                    float vv = h1 / (1.0f + __expf(-h1)) * h3;
                    int col = n0 + wn * 64 + ni * 16 + fr;
                    pout[(size_t)prow * FDIM + col] = (bf16_t)vv;
                }
            }
        }
    }
}

// GEMM2 merged + fused-K + split-K=2 (single-writer per target buffer):
//   split 0: out [perm[row]]  = sum over K in [0,1408)
//   split 1: outP[perm[row]]  = sum over K in [1408,2816)
// then out += outP (add_out_kernel). 1024 active blocks, 22 K-steps each.
__global__ __launch_bounds__(256, 2)
void gemm2m_bf16(const bf16_t* __restrict__ mid_r, const bf16_t* __restrict__ mid_s,
                 const bf16_t* __restrict__ w2T, const bf16_t* __restrict__ ws2T,
                 const int* __restrict__ perm, const int* __restrict__ offsets,
                 float* __restrict__ out, float* __restrict__ outP)
{
    const int e   = blockIdx.z;
    const int nb  = blockIdx.x & 15;
    const int spl = blockIdx.x >> 4;
    const int n0  = nb * 64;
    const int kLo = spl * KHALF;
    const int s   = offsets[e], eEnd = offsets[e + 1];
    const int m0  = s + blockIdx.y * 128;
    if (m0 >= eEnd) return;
    const int mEnd = eEnd;
    float* dst = spl ? outP : out;

    __shared__ __align__(16) bf16_t sAr[128 * 64];
    __shared__ __align__(16) bf16_t sAs[128 * 64];
    __shared__ __align__(16) bf16_t sBr[64 * 64];
    __shared__ __align__(16) bf16_t sBs[64 * 64];

    const int tid  = threadIdx.x;
    const int lane = tid & 63;
    const int wid  = tid >> 6;
    const int wm   = wid >> 1, wn = wid & 1;   // 2x2 waves: 64-row x 32-col tiles
    const int fr   = lane & 15;
    const int fq   = lane >> 4;

    f32x4 acc[4][2];
#pragma unroll
    for (int i = 0; i < 4; ++i)
#pragma unroll
        for (int j = 0; j < 2; ++j)
            acc[i][j] = (f32x4){0.f, 0.f, 0.f, 0.f};

    // per-thread gathered row pointers for the shared contribution
    const int baseRow = tid >> 3;
    const bf16_t* rowPtr[4];
#pragma unroll
    for (int i = 0; i < 4; ++i) {
        int rr = m0 + baseRow + 32 * i;
        int tok = perm[rr < mEnd ? rr : m0];   // clamp: garbage rows masked at store
        rowPtr[i] = mid_s + (size_t)tok * FDIM + kLo;
    }

    const bf16_t* srcAr = mid_r + (size_t)m0 * FDIM + kLo;
    const bf16_t* srcBr = w2T + (size_t)e * DDIM * FDIM + (size_t)n0 * FDIM + kLo;
    const bf16_t* srcBs = ws2T + (size_t)n0 * FDIM + kLo;

    for (int k0 = 0; k0 < KHALF; k0 += 64) {
        stage_swz(srcAr + k0, FDIM, sAr, tid);
        stage_swz_gather(rowPtr, k0, sAs, tid);
        stage_swz64(srcBr + k0, FDIM, sBr, tid);
        stage_swz64(srcBs + k0, FDIM, sBs, tid);
        __syncthreads();

#pragma unroll
        for (int ss = 0; ss < 2; ++ss) {
            const int kg = ss * 4 + fq;
            bf16x8 ar[4], br[2], as[4], bs[2];
#pragma unroll
            for (int mi = 0; mi < 4; ++mi) {
                int r = wm * 64 + mi * 16 + fr;
                ar[mi] = *(const bf16x8*)((const char*)sAr + swz_off(r, kg));
                as[mi] = *(const bf16x8*)((const char*)sAs + swz_off(r, kg));
            }
#pragma unroll
            for (int ni = 0; ni < 2; ++ni) {
                int r = wn * 32 + ni * 16 + fr;
                br[ni] = *(const bf16x8*)((const char*)sBr + swz_off(r, kg));
                bs[ni] = *(const bf16x8*)((const char*)sBs + swz_off(r, kg));
            }
#pragma unroll
            for (int mi = 0; mi < 4; ++mi)
#pragma unroll
                for (int ni = 0; ni < 2; ++ni) {
                    acc[mi][ni] = __builtin_amdgcn_mfma_f32_16x16x32_bf16(ar[mi], br[ni], acc[mi][ni], 0, 0, 0);
                    acc[mi][ni] = __builtin_amdgcn_mfma_f32_16x16x32_bf16(as[mi], bs[ni], acc[mi][ni], 0, 0, 0);
                }
        }
        __syncthreads();
    }

#pragma unroll
    for (int mi = 0; mi < 4; ++mi) {
        int prow_b = m0 + wm * 64 + mi * 16 + fq * 4;
#pragma unroll
        for (int r = 0; r < 4; ++r) {
            int prow = prow_b + r;
            if (prow < mEnd) {
                int orow = perm[prow];
#pragma unroll
                for (int ni = 0; ni < 2; ++ni) {
                    int col = n0 + wn * 32 + ni * 16 + fr;
                    dst[(size_t)orow * DDIM + col] = acc[mi][ni][r];
                }
            }
        }
    }
}

// out += outP, vectorized
__global__ __launch_bounds__(256)
void add_out_kernel(float* __restrict__ out, const float* __restrict__ outP)
{
    const size_t i = ((size_t)blockIdx.x * 256 + threadIdx.x) * 4;
    float4 a = *(const float4*)(out + i);
    float4 b = *(const float4*)(outP + i);
    a.x += b.x; a.y += b.y; a.z += b.z; a.w += b.w;
    *(float4*)(out + i) = a;
}

// ======================= launch =======================
extern "C" void kernel_launch(void* const* d_in, const int* in_sizes, int n_in,
                              void* d_out, int out_size, void* d_ws, size_t ws_size,
                              hipStream_t stream)
{
    const float* x      = (const float*)d_in[0];
    const float* router = (const float*)d_in[1];
    const float* w1     = (const float*)d_in[2];
    const float* w3     = (const float*)d_in[3];
    const float* w2     = (const float*)d_in[4];
    const float* ws1    = (const float*)d_in[5];
    const float* ws3    = (const float*)d_in[6];
    const float* ws2    = (const float*)d_in[7];
    float* out = (float*)d_out;

    char* ws = (char*)d_ws;
    int*   idx_a   = (int*)(ws + 0);
    float* gate_a  = (float*)(ws + 16384);
    int*   offsets = (int*)(ws + 32832);
    int*   perm    = (int*)(ws + 33280);

    bf16_t* xs    = (bf16_t*)(ws + OFF_XS);
    bf16_t* xr    = (bf16_t*)(ws + OFF_XR);
    bf16_t* mid_s = (bf16_t*)(ws + OFF_MIDS);
    bf16_t* mid_r = (bf16_t*)(ws + OFF_MIDR);
    bf16_t* w1T   = (bf16_t*)(ws + OFF_W1T);
    bf16_t* w3T   = (bf16_t*)(ws + OFF_W3T);
    bf16_t* w2T   = (bf16_t*)(ws + OFF_W2T);
    bf16_t* ws1T  = (bf16_t*)(ws + OFF_WS1T);
    bf16_t* ws3T  = (bf16_t*)(ws + OFF_WS3T);
    bf16_t* ws2T  = (bf16_t*)(ws + OFF_WS2T);
    float*  outP  = (float*)(ws + OFF_OUTP);   // aliases w1T (dead after gemm1)

    score_kernel<<<A_TOK / 4, 256, 0, stream>>>(x, router, idx_a, gate_a);
    perm_kernel<<<1, 1024, 0, stream>>>(idx_a, offsets, perm);

    prep_x_kernel<<<A_TOK, 256, 0, stream>>>(x, gate_a, perm, xs, xr);
    tconvA_kernel<<<dim3(FDIM / 64, DDIM / 64, 18), 256, 0, stream>>>(
        w1, w3, ws1, ws3, w1T, w3T, ws1T, ws3T);

    gemm1_bf16<<<dim3(FDIM / 128, 32, NEXP + 1), 256, 0, stream>>>(
        xr, xs, w1T, w3T, ws1T, ws3T, offsets, mid_r, mid_s);

    tconvB_kernel<<<dim3(DDIM / 64, FDIM / 64, 9), 256, 0, stream>>>(
        w2, ws2, w2T, ws2T);

    gemm2m_bf16<<<dim3(32, 32, NEXP), 256, 0, stream>>>(
        mid_r, mid_s, w2T, ws2T, perm, offsets, out, outP);

    add_out_kernel<<<(A_TOK * DDIM) / (256 * 4), 256, 0, stream>>>(out, outP);
}